// Round 6
// baseline (650.900 us; speedup 1.0000x reference)
//
#include <hip/hip_runtime.h>
#include <hip/hip_bf16.h>

// ---- problem constants ----
#define BSZ 4
#define TT 64
#define NNODE 128
#define NFEAT 16
#define HIDD 64
#define NHEAD 4
#define RHID 256
#define LDIM 64
#define EPG 1024
#define NGRAPH (BSZ*TT)          // 256
#define NTOT (NGRAPH*NNODE)      // 32768
#define ESLOTS (EPG+NNODE)       // 1152

// ---- canonical fp32 weight buffer offsets (floats) ----
#define WOFF_G0W 0
#define WOFF_G0AS 4096
#define WOFF_G0AD 4352
#define WOFF_G0B 4608
#define WOFF_G1W 4864
#define WOFF_G1AS 70400
#define WOFF_G1AD 70656
#define WOFF_G1B 70912
#define WOFF_G2W 71168
#define WOFF_G2AS 87552
#define WOFF_G2AD 87616
#define WOFF_G2B 87680
#define WOFF_WIHF 87744
#define WOFF_WHHF 153280
#define WOFF_BIHF 415424
#define WOFF_BHHF 416448
#define WOFF_WIHB 417472
#define WOFF_WHHB 483008
#define WOFF_BIHB 745152
#define WOFF_BHHB 746176
#define WOFF_MUW 747200
#define WOFF_MUB 779968
#define WOFF_LVW 780032
#define WOFF_LVB 812800
#define WTOTAL   812864

// ---- workspace float offsets ----
#define FOFF_WBUF 4096
#define FOFF_CSR  1052672      // csr_row int[132], csr_src u16[1152]
#define FOFF_WE   1576960      // WTB (bf16 B-frag Whh, 262144 uints)
#define FOFF_BBF  1900000      // bf16 B matrices (u16 view)
#define FOFF_XFP  2756608
#define FOFF_XBP  3018752
#define FOFF_HT   3280896
#define FOFF_XSEQ 3282944
#define FOFF_PA   3291136      // P0 [32768][256] bf16
#define FOFF_PB   5388288      // P1 [32768][256] bf16
#define FOFF_P    7485440      // X  [32768][16]  bf16

// bf16 B-matrix u16 offsets inside BBF (G0/G1/G2 stored TRANSPOSED [out][in])
#define BOFF_G0 0
#define BOFF_G1 4096
#define BOFF_G2 69632
#define BOFF_WF 86016
#define BOFF_WB 151552
#define BTOTAL  217088

// setup phases
#define SP_CVTX  (WTOTAL + BTOTAL)            // 1029952
#define SP_WHH   (SP_CVTX + NTOT*NFEAT)       // 1554240
#define SP_TOTAL (SP_WHH + 262144)            // 1816384

typedef __attribute__((ext_vector_type(8))) short short8;
typedef __attribute__((ext_vector_type(4))) float float4v;

__device__ __forceinline__ float b2f(unsigned short u){
  union { unsigned int i; float f; } v; v.i = ((unsigned int)u) << 16; return v.f;
}
__device__ __forceinline__ unsigned short f2b(float f){
  __hip_bfloat16 h = __float2bfloat16(f);
  union { __hip_bfloat16 h; unsigned short u; } v; v.h = h; return v.u;
}
__device__ __forceinline__ float ldf(const void* p, int i, int flag){
  return flag ? b2f(((const unsigned short*)p)[i]) : ((const float*)p)[i];
}
__device__ __forceinline__ float h2f(unsigned short s){
  union { _Float16 hh; unsigned short s; } u; u.s = s; return (float)u.hh;
}
__device__ __forceinline__ unsigned short f2h(float f){
  union { _Float16 hh; unsigned short s; } u; u.hh = (_Float16)f; return u.s;
}
__device__ __forceinline__ int sniff32(const unsigned short* w){
  int ok = 0;
  #pragma unroll
  for (int i = 0; i < 32; ++i){
    float a = fabsf(b2f(w[2 * i]));
    if (a > 1e-8f && a < 4.f) ok++;
  }
  return ok >= 16 ? 1 : 0;
}

// ---------------- fused setup: sniff + cvtw + packb(T) + cvtx + packwhh + CSR ----------------
struct CvtArgs {
  const void* src[24];
  int off[25];
};
__global__ void setup_kernel(CvtArgs a,
                             float* __restrict__ W, unsigned short* __restrict__ BBF,
                             unsigned short* __restrict__ P, unsigned int* __restrict__ WT,
                             const void* __restrict__ x, const int* __restrict__ ei,
                             int* __restrict__ csr_row, unsigned short* __restrict__ csr_src)
{
  __shared__ int cnt[NNODE];
  __shared__ int off[NNODE];
  __shared__ int wo[NNODE];
  const int tid = threadIdx.x;

  if (blockIdx.x == gridDim.x - 1){
    if (tid < NNODE) cnt[tid] = 0;
    __syncthreads();
    for (int i = tid; i < ESLOTS; i += 256){
      int d = (i < EPG) ? ei[EPG + i] : (i - EPG);
      atomicAdd(&cnt[d], 1);
    }
    __syncthreads();
    if (tid < NNODE) off[tid] = cnt[tid];
    for (int o = 1; o < NNODE; o <<= 1){
      __syncthreads();
      int t = (tid < NNODE && tid >= o) ? off[tid - o] : 0;
      __syncthreads();
      if (tid < NNODE) off[tid] += t;
    }
    __syncthreads();
    if (tid < NNODE){
      wo[tid] = off[tid] - cnt[tid];
      csr_row[tid + 1] = off[tid];
    }
    if (tid == 0) csr_row[0] = 0;
    __syncthreads();
    for (int i = tid; i < ESLOTS; i += 256){
      int s, d;
      if (i < EPG){ s = ei[i]; d = ei[EPG + i]; } else { s = i - EPG; d = i - EPG; }
      int pos = atomicAdd(&wo[d], 1);
      csr_src[pos] = (unsigned short)s;
    }
    return;
  }

  int id = blockIdx.x * blockDim.x + tid;
  if (id >= SP_TOTAL) return;
  int fl = sniff32((const unsigned short*)a.src[0]);
  if (id < WTOTAL){
    int k = 0;
    while (id >= a.off[k + 1]) ++k;
    W[id] = ldf(a.src[k], id - a.off[k], fl);
  } else if (id < WTOTAL + BTOTAL){
    int r = id - WTOTAL;
    float v;
    if (r < BOFF_G1){
      int o = r >> 4, k = r & 15;
      v = ldf(a.src[0], k * 256 + o, fl);
    } else if (r < BOFF_G2){
      int rr = r - BOFF_G1; int o = rr >> 8, k = rr & 255;
      v = ldf(a.src[4], k * 256 + o, fl);
    } else if (r < BOFF_WF){
      int rr = r - BOFF_G2; int o = rr >> 8, k = rr & 255;
      v = ldf(a.src[8], k * 64 + o, fl);
    } else if (r < BOFF_WB){
      int q = r - BOFF_WF; int k = q >> 10, n = q & 1023;
      v = ldf(a.src[12], n * 64 + k, fl);
    } else {
      int q = r - BOFF_WB; int k = q >> 10, n = q & 1023;
      v = ldf(a.src[16], n * 64 + k, fl);
    }
    BBF[r] = f2b(v);
  } else if (id < SP_CVTX + NTOT * NFEAT){
    int r = id - SP_CVTX;
    P[r] = fl ? ((const unsigned short*)x)[r] : f2b(((const float*)x)[r]);
  } else {
    // Whh B-fragment pack for the single-CU LSTM:
    // uint4 index q4 = dir*32768 + ((kc*8 + wid)*8 + nt8)*64 + lane, word c.
    // lane (q=lane>>4, r=lane&15) holds W[row = wid*128 + nt8*16 + r][k = kc*32 + q*8 + 2c .. +1]
    int r0 = id - SP_WHH;
    int c = r0 & 3;
    int q4 = r0 >> 2;
    int lane = q4 & 63;
    int nt8 = (q4 >> 6) & 7;
    int wid = (q4 >> 9) & 7;
    int kc = (q4 >> 12) & 7;
    int dir = q4 >> 15;
    int u = wid * 128 + nt8 * 16 + (lane & 15);
    int k0 = kc * 32 + ((lane >> 4) << 3) + 2 * c;
    const void* Wsrc = dir ? a.src[17] : a.src[13];
    unsigned short va = f2b(ldf(Wsrc, u * RHID + k0, fl));
    unsigned short vb = f2b(ldf(Wsrc, u * RHID + k0 + 1, fl));
    WT[r0] = (unsigned int)va | ((unsigned int)vb << 16);
  }
}

// ---------------- GAT 4-head half-layer kernel (L0/L1): 512 blocks, MFMA agg, plain stores ----------------
template<int KV>
__global__ __launch_bounds__(256)
void glayer_kernel(const unsigned short* __restrict__ Pin,
                   const unsigned short* __restrict__ BT,
                   const float* __restrict__ Wbuf,
                   int asoff, int adoff, int boff,
                   const int* __restrict__ csr_row, const unsigned short* __restrict__ csr_src,
                   unsigned short* __restrict__ Pout)
{
  __shared__ unsigned short HT_[128 * 136];   // h^T [col][node]
  __shared__ unsigned short AD[128 * 136];    // union: Bst / dense-alpha [dst][src]
  __shared__ unsigned short ALS16[256];
  __shared__ unsigned short ALD16[256];
  __shared__ int   rowL[132];
  __shared__ unsigned char srcL[1152];

  const int tid = threadIdx.x;
  const int g = blockIdx.x >> 1, hb = blockIdx.x & 1;
  const int c0 = hb * 128;
  const int w = tid >> 6, lane = tid & 63, q = lane >> 4, r = lane & 15;
  unsigned short* Bst = AD;

  for (int i = tid; i < 129; i += 256) rowL[i] = csr_row[i];
  for (int i = tid; i < 1152; i += 256) srcL[i] = (unsigned char)csr_src[i];
  __syncthreads();

  // ---- GEMM producing h^T ----
  {
    float4v acc0[8], acc1[8];
    #pragma unroll
    for (int i = 0; i < 8; ++i){ acc0[i] = (float4v){0,0,0,0}; acc1[i] = (float4v){0,0,0,0}; }
    const int KR = (KV + 31) / 32;
    for (int kr = 0; kr < KR; ++kr){
      const int kc = kr * 32;
      __syncthreads();
      {
        int n = tid >> 1, kb = (tid & 1) * 16;
        uint4 z = {0,0,0,0}; uint4 v0 = z, v1 = z;
        if (kb < KV)     v0 = *(const uint4*)(BT + (size_t)(c0 + n) * KV + kc + kb);
        if (kb + 8 < KV) v1 = *(const uint4*)(BT + (size_t)(c0 + n) * KV + kc + kb + 8);
        *(uint4*)&Bst[n * 40 + kb] = v0;
        *(uint4*)&Bst[n * 40 + kb + 8] = v1;
      }
      short8 a0 = {0,0,0,0,0,0,0,0}, a1 = {0,0,0,0,0,0,0,0};
      if (KV >= 32 || q < 2){
        a0 = *(const short8*)(Pin + (size_t)(g * 128 + 16 * w       + r) * KV + kc + q * 8);
        a1 = *(const short8*)(Pin + (size_t)(g * 128 + 16 * (w + 4) + r) * KV + kc + q * 8);
      }
      __syncthreads();
      #pragma unroll
      for (int nt = 0; nt < 8; ++nt){
        short8 bf = *(const short8*)&Bst[(16 * nt + r) * 40 + q * 8];
        acc0[nt] = __builtin_amdgcn_mfma_f32_16x16x32_bf16(a0, bf, acc0[nt], 0, 0, 0);
        acc1[nt] = __builtin_amdgcn_mfma_f32_16x16x32_bf16(a1, bf, acc1[nt], 0, 0, 0);
      }
    }
    __syncthreads();
    #pragma unroll
    for (int nt = 0; nt < 8; ++nt)
      #pragma unroll
      for (int i = 0; i < 4; ++i){
        HT_[(16 * nt + r) * 136 + 16 * w       + q * 4 + i] = f2b(acc0[nt][i]);
        HT_[(16 * nt + r) * 136 + 16 * (w + 4) + q * 4 + i] = f2b(acc1[nt][i]);
      }
    __syncthreads();
  }

  // ---- attention logits (2 local heads) ----
  {
    float as0 = Wbuf[asoff + c0 + 2 * lane], as1 = Wbuf[asoff + c0 + 2 * lane + 1];
    float ad0 = Wbuf[adoff + c0 + 2 * lane], ad1 = Wbuf[adoff + c0 + 2 * lane + 1];
    for (int it = 0; it < 32; ++it){
      int n = it * 4 + w;
      float e0 = b2f(HT_[(2 * lane) * 136 + n]);
      float e1 = b2f(HT_[(2 * lane + 1) * 136 + n]);
      float vs = e0 * as0 + e1 * as1;
      float vd = e0 * ad0 + e1 * ad1;
      #pragma unroll
      for (int m = 16; m >= 1; m >>= 1){ vs += __shfl_xor(vs, m); vd += __shfl_xor(vd, m); }
      if ((lane & 31) == 0){
        ALS16[n * 2 + (lane >> 5)] = f2h(vs);
        ALD16[n * 2 + (lane >> 5)] = f2h(vd);
      }
    }
  }
  __syncthreads();

  // ---- per-head: dense softmax scatter + MFMA agg + plain-store epilogue ----
  for (int hl = 0; hl < 2; ++hl){
    for (int i = tid; i < 8704; i += 256) ((unsigned int*)AD)[i] = 0;
    __syncthreads();
    if (tid < 128){
      int n = tid;
      float aldv = h2f(ALD16[n * 2 + hl]);
      int rs = rowL[n], re = rowL[n + 1];
      float mx = -3e38f, den = 0.f;
      for (int j = rs; j < re; ++j){
        float v = h2f(ALS16[srcL[j] * 2 + hl]) + aldv;
        v = v > 0.f ? v : 0.2f * v;
        if (v > mx){ den = den * __expf(mx - v) + 1.f; mx = v; }
        else den += __expf(v - mx);
      }
      float iden = 1.f / (den + 1e-16f);
      for (int j = rs; j < re; ++j){
        float v = h2f(ALS16[srcL[j] * 2 + hl]) + aldv;
        v = v > 0.f ? v : 0.2f * v;
        float al = __expf(v - mx) * iden;
        int s = srcL[j];
        AD[n * 136 + s] = f2b(b2f(AD[n * 136 + s]) + al);
      }
    }
    __syncthreads();
    float4v am[2][4];
    #pragma unroll
    for (int mt = 0; mt < 2; ++mt)
      #pragma unroll
      for (int nt = 0; nt < 4; ++nt) am[mt][nt] = (float4v){0,0,0,0};
    #pragma unroll
    for (int kc = 0; kc < 4; ++kc){
      short8 af0 = *(const short8*)&AD[(w * 32      + r) * 136 + kc * 32 + q * 8];
      short8 af1 = *(const short8*)&AD[(w * 32 + 16 + r) * 136 + kc * 32 + q * 8];
      #pragma unroll
      for (int nt = 0; nt < 4; ++nt){
        short8 bf = *(const short8*)&HT_[(hl * 64 + nt * 16 + r) * 136 + kc * 32 + q * 8];
        am[0][nt] = __builtin_amdgcn_mfma_f32_16x16x32_bf16(af0, bf, am[0][nt], 0, 0, 0);
        am[1][nt] = __builtin_amdgcn_mfma_f32_16x16x32_bf16(af1, bf, am[1][nt], 0, 0, 0);
      }
    }
    #pragma unroll
    for (int mt = 0; mt < 2; ++mt)
      #pragma unroll
      for (int nt = 0; nt < 4; ++nt){
        int col = hl * 64 + nt * 16 + r;
        float bz = Wbuf[boff + c0 + col];
        #pragma unroll
        for (int i = 0; i < 4; ++i){
          int dst = w * 32 + mt * 16 + q * 4 + i;
          float v = am[mt][nt][i] + bz;
          v = v > 0.f ? v : 0.f;
          Pout[(size_t)(g * 128 + dst) * 256 + c0 + col] = f2b(v);
        }
      }
    __syncthreads();
  }
}

// ---------------- GAT layer 2 (1 head) + pool: 512 blocks ----------------
__global__ __launch_bounds__(256)
void glayer2_kernel(const unsigned short* __restrict__ Pin,
                    const unsigned short* __restrict__ BT,
                    const float* __restrict__ Wbuf,
                    const int* __restrict__ csr_row, const unsigned short* __restrict__ csr_src,
                    unsigned short* __restrict__ XSEQ)
{
  __shared__ unsigned short HT_[64 * 136];
  __shared__ unsigned short AD[128 * 136];
  __shared__ float ALSf[128];
  __shared__ float ALDf[128];
  __shared__ int   rowL[132];
  __shared__ unsigned char srcL[1152];
  __shared__ float pools[4][64];

  const int tid = threadIdx.x;
  const int g = blockIdx.x >> 1, hb = blockIdx.x & 1;
  const int w = tid >> 6, lane = tid & 63, q = lane >> 4, r = lane & 15;
  unsigned short* Bst = AD;

  for (int i = tid; i < 129; i += 256) rowL[i] = csr_row[i];
  for (int i = tid; i < 1152; i += 256) srcL[i] = (unsigned char)csr_src[i];
  __syncthreads();

  // ---- GEMM h2^T [64 cols][128 nodes] ----
  {
    float4v acc0[4], acc1[4];
    #pragma unroll
    for (int i = 0; i < 4; ++i){ acc0[i] = (float4v){0,0,0,0}; acc1[i] = (float4v){0,0,0,0}; }
    for (int kr = 0; kr < 8; ++kr){
      const int kc = kr * 32;
      __syncthreads();
      {
        int n = tid >> 2, kb = (tid & 3) * 8;
        uint4 v = *(const uint4*)(BT + (size_t)n * 256 + kc + kb);
        *(uint4*)&Bst[n * 40 + kb] = v;
      }
      short8 a0 = *(const short8*)(Pin + (size_t)(g * 128 + 16 * w       + r) * 256 + kc + q * 8);
      short8 a1 = *(const short8*)(Pin + (size_t)(g * 128 + 16 * (w + 4) + r) * 256 + kc + q * 8);
      __syncthreads();
      #pragma unroll
      for (int nt = 0; nt < 4; ++nt){
        short8 bf = *(const short8*)&Bst[(16 * nt + r) * 40 + q * 8];
        acc0[nt] = __builtin_amdgcn_mfma_f32_16x16x32_bf16(a0, bf, acc0[nt], 0, 0, 0);
        acc1[nt] = __builtin_amdgcn_mfma_f32_16x16x32_bf16(a1, bf, acc1[nt], 0, 0, 0);
      }
    }
    __syncthreads();
    #pragma unroll
    for (int nt = 0; nt < 4; ++nt)
      #pragma unroll
      for (int i = 0; i < 4; ++i){
        HT_[(16 * nt + r) * 136 + 16 * w       + q * 4 + i] = f2b(acc0[nt][i]);
        HT_[(16 * nt + r) * 136 + 16 * (w + 4) + q * 4 + i] = f2b(acc1[nt][i]);
      }
    __syncthreads();
  }

  // ---- attention (64 cols) ----
  {
    float asv = Wbuf[WOFF_G2AS + lane];
    float adv = Wbuf[WOFF_G2AD + lane];
    for (int it = 0; it < 32; ++it){
      int n = it * 4 + w;
      float e0 = b2f(HT_[lane * 136 + n]);
      float vs = e0 * asv, vd = e0 * adv;
      #pragma unroll
      for (int m = 32; m >= 1; m >>= 1){ vs += __shfl_xor(vs, m); vd += __shfl_xor(vd, m); }
      if (lane == 0){ ALSf[n] = vs; ALDf[n] = vd; }
    }
  }
  __syncthreads();
  for (int i = tid; i < 8704; i += 256) ((unsigned int*)AD)[i] = 0;
  __syncthreads();
  if (tid < 128){
    int n = tid;
    float aldv = ALDf[n];
    int rs = rowL[n], re = rowL[n + 1];
    float mx = -3e38f, den = 0.f;
    for (int j = rs; j < re; ++j){
      float v = ALSf[srcL[j]] + aldv;
      v = v > 0.f ? v : 0.2f * v;
      if (v > mx){ den = den * __expf(mx - v) + 1.f; mx = v; }
      else den += __expf(v - mx);
    }
    float iden = 1.f / (den + 1e-16f);
    for (int j = rs; j < re; ++j){
      float v = ALSf[srcL[j]] + aldv;
      v = v > 0.f ? v : 0.2f * v;
      float al = __expf(v - mx) * iden;
      int s = srcL[j];
      AD[n * 136 + s] = f2b(b2f(AD[n * 136 + s]) + al);
    }
  }
  __syncthreads();
  float4v am[2][4];
  #pragma unroll
  for (int mt = 0; mt < 2; ++mt)
    #pragma unroll
    for (int nt = 0; nt < 4; ++nt) am[mt][nt] = (float4v){0,0,0,0};
  #pragma unroll
  for (int kc = 0; kc < 4; ++kc){
    short8 af0 = *(const short8*)&AD[(w * 32      + r) * 136 + kc * 32 + q * 8];
    short8 af1 = *(const short8*)&AD[(w * 32 + 16 + r) * 136 + kc * 32 + q * 8];
    #pragma unroll
    for (int nt = 0; nt < 4; ++nt){
      short8 bf = *(const short8*)&HT_[(nt * 16 + r) * 136 + kc * 32 + q * 8];
      am[0][nt] = __builtin_amdgcn_mfma_f32_16x16x32_bf16(af0, bf, am[0][nt], 0, 0, 0);
      am[1][nt] = __builtin_amdgcn_mfma_f32_16x16x32_bf16(af1, bf, am[1][nt], 0, 0, 0);
    }
  }
  float psum[4] = {0.f, 0.f, 0.f, 0.f};
  #pragma unroll
  for (int nt = 0; nt < 4; ++nt){
    int col = nt * 16 + r;
    float bz = Wbuf[WOFF_G2B + col];
    #pragma unroll
    for (int mt = 0; mt < 2; ++mt)
      #pragma unroll
      for (int i = 0; i < 4; ++i){
        float v = am[mt][nt][i] + bz;
        psum[nt] += (v > 0.f ? v : 0.f);
      }
    psum[nt] += __shfl_xor(psum[nt], 16);
    psum[nt] += __shfl_xor(psum[nt], 32);
  }
  if (q == 0){
    #pragma unroll
    for (int nt = 0; nt < 4; ++nt) pools[w][nt * 16 + r] = psum[nt];
  }
  __syncthreads();
  if (tid < 64 && (tid >> 5) == hb){
    float s = pools[0][tid] + pools[1][tid] + pools[2][tid] + pools[3][tid];
    int b = g >> 6, tq = g & 63;
    XSEQ[(size_t)(tq * BSZ + b) * HIDD + tid] = f2b(s);
  }
}

// ---------------- MFMA matmul for BOTH Wih GEMMs + bias fold (z = dir) ----------------
__global__ __launch_bounds__(256)
void mmx2_kernel(const unsigned short* __restrict__ A,
                 const unsigned short* __restrict__ B0, const unsigned short* __restrict__ B1,
                 const float* __restrict__ biF, const float* __restrict__ bhF,
                 const float* __restrict__ biB, const float* __restrict__ bhB,
                 float* __restrict__ C0, float* __restrict__ C1, int M, int Nc, int K)
{
  __shared__ unsigned short As[64][40];
  __shared__ unsigned short Bs[64][40];
  const unsigned short* Bb = blockIdx.z ? B1 : B0;
  float* C = blockIdx.z ? C1 : C0;
  const float* bi = blockIdx.z ? biB : biF;
  const float* bh = blockIdx.z ? bhB : bhF;
  const int tid = threadIdx.x;
  const int w = tid >> 6, lane = tid & 63, q = lane >> 4, r = lane & 15;
  const int m0 = blockIdx.x * 64, n0 = blockIdx.y * 64;
  float4v acc0 = {0,0,0,0}, acc1 = {0,0,0,0}, acc2 = {0,0,0,0}, acc3 = {0,0,0,0};
  const int arow = tid >> 2, akb = (tid & 3) * 8;
  const int bk = tid >> 3, bnb = (tid & 7) * 8;
  for (int kc = 0; kc < K; kc += 32){
    int kw = K - kc; if (kw > 32) kw = 32;
    if (akb < kw){
      uint4 v = *(const uint4*)(A + (size_t)(m0 + arow) * K + kc + akb);
      *(uint4*)&As[arow][akb] = v;
    } else {
      uint4 z = {0,0,0,0}; *(uint4*)&As[arow][akb] = z;
    }
    if (bk < kw){
      uint4 v = *(const uint4*)(Bb + (size_t)(kc + bk) * Nc + n0 + bnb);
      const unsigned short* vs = (const unsigned short*)&v;
      #pragma unroll
      for (int e = 0; e < 8; ++e) Bs[bnb + e][bk] = vs[e];
    } else {
      #pragma unroll
      for (int e = 0; e < 8; ++e) Bs[bnb + e][bk] = 0;
    }
    __syncthreads();
    short8 af = *(const short8*)&As[16 * w + r][q * 8];
    short8 b0 = *(const short8*)&Bs[r][q * 8];
    short8 b1 = *(const short8*)&Bs[16 + r][q * 8];
    short8 b2 = *(const short8*)&Bs[32 + r][q * 8];
    short8 b3 = *(const short8*)&Bs[48 + r][q * 8];
    acc0 = __builtin_amdgcn_mfma_f32_16x16x32_bf16(af, b0, acc0, 0, 0, 0);
    acc1 = __builtin_amdgcn_mfma_f32_16x16x32_bf16(af, b1, acc1, 0, 0, 0);
    acc2 = __builtin_amdgcn_mfma_f32_16x16x32_bf16(af, b2, acc2, 0, 0, 0);
    acc3 = __builtin_amdgcn_mfma_f32_16x16x32_bf16(af, b3, acc3, 0, 0, 0);
    __syncthreads();
  }
  const int row = m0 + 16 * w + q * 4, col0 = n0 + r;
  const float bz0 = bi[col0]      + bh[col0];
  const float bz1 = bi[col0 + 16] + bh[col0 + 16];
  const float bz2 = bi[col0 + 32] + bh[col0 + 32];
  const float bz3 = bi[col0 + 48] + bh[col0 + 48];
  #pragma unroll
  for (int i = 0; i < 4; ++i){
    size_t base = (size_t)(row + i) * Nc;
    C[base + col0]      = acc0[i] + bz0;
    C[base + col0 + 16] = acc1[i] + bz1;
    C[base + col0 + 32] = acc2[i] + bz2;
    C[base + col0 + 48] = acc3[i] + bz3;
  }
}

// ---------------- LSTM on ONE CU per direction, 256 threads (1 wave/SIMD, 512-reg budget) ----------------
// grid=2, 256 threads = 4 waves. __launch_bounds__(256,1) -> up to 512 regs/wave.
// Whh: K-chunks 0-1 in LDS (128 KB, r4/r5-verified layout); K-chunks 2-7 in 96 named
// uint4 per lane (384 regs) -- inside the proven no-spill zone (~450). Wave w owns
// gate rows [w*256,(w+1)*256) = 16 N-tiles, processed as 2 groups of 8 accumulators.
#define MFMA16 __builtin_amdgcn_mfma_f32_16x16x32_bf16
#define BC8(x) __builtin_bit_cast(short8, x)

#define DECLJ(j) uint4 W##j##_0, W##j##_1, W##j##_2, W##j##_3, W##j##_4, W##j##_5;
#define RIDX(j,kk) (((((kk) + 2) * 8 + w2 + ((j) >> 3)) * 8 + ((j) & 7)) * 64 + lane)
#define LDJ(j) W##j##_0 = WT4[RIDX(j,0)]; W##j##_1 = WT4[RIDX(j,1)]; W##j##_2 = WT4[RIDX(j,2)]; \
               W##j##_3 = WT4[RIDX(j,3)]; W##j##_4 = WT4[RIDX(j,4)]; W##j##_5 = WT4[RIDX(j,5)];
#define LIDX(j,kc) ((((kc) * 8 + w2 + ((j) >> 3)) * 8 + ((j) & 7)) * 64 + lane)

// group A = j 0..7, group B = j 8..15
#define GA_LDS(kc) { short8 af = BC8(H16u4[r * 33 + (kc) * 4 + quad]); \
  a0 = MFMA16(af, BC8(WL4[LIDX(0,kc)]), a0,0,0,0); a1 = MFMA16(af, BC8(WL4[LIDX(1,kc)]), a1,0,0,0); \
  a2 = MFMA16(af, BC8(WL4[LIDX(2,kc)]), a2,0,0,0); a3 = MFMA16(af, BC8(WL4[LIDX(3,kc)]), a3,0,0,0); \
  a4 = MFMA16(af, BC8(WL4[LIDX(4,kc)]), a4,0,0,0); a5 = MFMA16(af, BC8(WL4[LIDX(5,kc)]), a5,0,0,0); \
  a6 = MFMA16(af, BC8(WL4[LIDX(6,kc)]), a6,0,0,0); a7 = MFMA16(af, BC8(WL4[LIDX(7,kc)]), a7,0,0,0); }
#define GA_REG(kk) { short8 af = BC8(H16u4[r * 33 + ((kk) + 2) * 4 + quad]); \
  a0 = MFMA16(af, BC8(W0_##kk), a0,0,0,0); a1 = MFMA16(af, BC8(W1_##kk), a1,0,0,0); \
  a2 = MFMA16(af, BC8(W2_##kk), a2,0,0,0); a3 = MFMA16(af, BC8(W3_##kk), a3,0,0,0); \
  a4 = MFMA16(af, BC8(W4_##kk), a4,0,0,0); a5 = MFMA16(af, BC8(W5_##kk), a5,0,0,0); \
  a6 = MFMA16(af, BC8(W6_##kk), a6,0,0,0); a7 = MFMA16(af, BC8(W7_##kk), a7,0,0,0); }
#define GB_LDS(kc) { short8 af = BC8(H16u4[r * 33 + (kc) * 4 + quad]); \
  a0 = MFMA16(af, BC8(WL4[LIDX(8,kc)]), a0,0,0,0);  a1 = MFMA16(af, BC8(WL4[LIDX(9,kc)]), a1,0,0,0); \
  a2 = MFMA16(af, BC8(WL4[LIDX(10,kc)]), a2,0,0,0); a3 = MFMA16(af, BC8(WL4[LIDX(11,kc)]), a3,0,0,0); \
  a4 = MFMA16(af, BC8(WL4[LIDX(12,kc)]), a4,0,0,0); a5 = MFMA16(af, BC8(WL4[LIDX(13,kc)]), a5,0,0,0); \
  a6 = MFMA16(af, BC8(WL4[LIDX(14,kc)]), a6,0,0,0); a7 = MFMA16(af, BC8(WL4[LIDX(15,kc)]), a7,0,0,0); }
#define GB_REG(kk) { short8 af = BC8(H16u4[r * 33 + ((kk) + 2) * 4 + quad]); \
  a0 = MFMA16(af, BC8(W8_##kk), a0,0,0,0);  a1 = MFMA16(af, BC8(W9_##kk), a1,0,0,0); \
  a2 = MFMA16(af, BC8(W10_##kk), a2,0,0,0); a3 = MFMA16(af, BC8(W11_##kk), a3,0,0,0); \
  a4 = MFMA16(af, BC8(W12_##kk), a4,0,0,0); a5 = MFMA16(af, BC8(W13_##kk), a5,0,0,0); \
  a6 = MFMA16(af, BC8(W14_##kk), a6,0,0,0); a7 = MFMA16(af, BC8(W15_##kk), a7,0,0,0); }

#define STG(jl, a, base) if (quad == 0){ int cb = (base) + (jl) * 16 + r; \
  glds[cb] = a[0]; glds[1024 + cb] = a[1]; glds[2048 + cb] = a[2]; glds[3072 + cb] = a[3]; }

#define NONLIN(k, cs, hv) { \
  int cc = j0 + 64 * (k); \
  float gi = glds[b1024 + cc]       + xr[cc]; \
  float gf = glds[b1024 + 256 + cc] + xr[256 + cc]; \
  float gg = glds[b1024 + 512 + cc] + xr[512 + cc]; \
  float go = glds[b1024 + 768 + cc] + xr[768 + cc]; \
  float si = 1.f / (1.f + __expf(-gi)); \
  float sf = 1.f / (1.f + __expf(-gf)); \
  float so = 1.f / (1.f + __expf(-go)); \
  float tg = 1.f - 2.f / (1.f + __expf(2.f * gg)); \
  cs = sf * cs + si * tg; \
  float ch = 1.f - 2.f / (1.f + __expf(2.f * cs)); \
  hv = so * ch; }

#define PACK(k, hv) { unsigned int o = f2b(hv); \
  unsigned int p = ((unsigned int)__shfl_xor((int)o, 1)) & 0xffffu; \
  if ((j0 & 1) == 0) H16[b * 132 + (j0 >> 1) + 32 * (k)] = o | (p << 16); }

__global__ __launch_bounds__(256, 1)
void lstm1cu_kernel(const float* __restrict__ XF, const float* __restrict__ XB,
                    const unsigned int* __restrict__ WT,
                    float* __restrict__ HT)
{
  __shared__ unsigned int WLDS[32768];     // kc 0..1: ((kc*8+wid)*8+nt8)*64+lane (uint4 granular)
  __shared__ unsigned int H16[16 * 132];   // h rows 0-3 = batch, 4-15 = zero pad
  __shared__ float glds[4096];             // gates [4 batch][1024 gate rows]

  const int tid = threadIdx.x;
  const int dir = blockIdx.x;
  const int wave = tid >> 6, lane = tid & 63, quad = lane >> 4, r = lane & 15;
  const int w2 = wave * 2;
  const float* Xp = dir ? XB : XF;
  const int b = wave, j0 = lane;           // nonlinearity: batch = wave, col base = lane
  const int b1024 = b * 1024;

  const uint4* WT4 = (const uint4*)WT + (size_t)dir * 32768;
  {
    uint4* W4 = (uint4*)WLDS;
    #pragma unroll 4
    for (int s = 0; s < 32; ++s)
      W4[s * 256 + tid] = WT4[s * 256 + tid];
  }
  DECLJ(0) DECLJ(1) DECLJ(2)  DECLJ(3)  DECLJ(4)  DECLJ(5)  DECLJ(6)  DECLJ(7)
  DECLJ(8) DECLJ(9) DECLJ(10) DECLJ(11) DECLJ(12) DECLJ(13) DECLJ(14) DECLJ(15)
  LDJ(0) LDJ(1) LDJ(2)  LDJ(3)  LDJ(4)  LDJ(5)  LDJ(6)  LDJ(7)
  LDJ(8) LDJ(9) LDJ(10) LDJ(11) LDJ(12) LDJ(13) LDJ(14) LDJ(15)

  for (int i = tid; i < 16 * 132; i += 256) H16[i] = 0;
  float cs0 = 0.f, cs1 = 0.f, cs2 = 0.f, cs3 = 0.f;
  __syncthreads();

  const uint4* H16u4 = (const uint4*)H16;
  const uint4* WL4 = (const uint4*)WLDS;

  for (int t = 0; t < TT; ++t){
    const int tb = dir ? (TT - 1 - t) : t;

    // ---- recurrent GEMM: group A (gate rows wave*256 + [0,128)) ----
    {
      float4v a0 = {0,0,0,0}, a1 = {0,0,0,0}, a2 = {0,0,0,0}, a3 = {0,0,0,0};
      float4v a4 = {0,0,0,0}, a5 = {0,0,0,0}, a6 = {0,0,0,0}, a7 = {0,0,0,0};
      GA_LDS(0) GA_LDS(1)
      GA_REG(0) GA_REG(1) GA_REG(2) GA_REG(3) GA_REG(4) GA_REG(5)
      const int base = wave * 256;
      STG(0, a0, base) STG(1, a1, base) STG(2, a2, base) STG(3, a3, base)
      STG(4, a4, base) STG(5, a5, base) STG(6, a6, base) STG(7, a7, base)
    }
    // ---- group B (gate rows wave*256 + [128,256)) ----
    {
      float4v a0 = {0,0,0,0}, a1 = {0,0,0,0}, a2 = {0,0,0,0}, a3 = {0,0,0,0};
      float4v a4 = {0,0,0,0}, a5 = {0,0,0,0}, a6 = {0,0,0,0}, a7 = {0,0,0,0};
      GB_LDS(0) GB_LDS(1)
      GB_REG(0) GB_REG(1) GB_REG(2) GB_REG(3) GB_REG(4) GB_REG(5)
      const int base = wave * 256 + 128;
      STG(0, a0, base) STG(1, a1, base) STG(2, a2, base) STG(3, a3, base)
      STG(4, a4, base) STG(5, a5, base) STG(6, a6, base) STG(7, a7, base)
    }
    __syncthreads();

    // ---- nonlinearity: thread owns (batch=wave, cols j0+{0,64,128,192}) ----
    {
      const float* xr = Xp + (size_t)(tb * 4 + b) * 1024;
      float hv0, hv1, hv2, hv3;
      NONLIN(0, cs0, hv0)
      NONLIN(1, cs1, hv1)
      NONLIN(2, cs2, hv2)
      NONLIN(3, cs3, hv3)

      if (t == TT - 1){
        float* hp = HT + (size_t)(dir * 4 + b) * RHID + j0;
        hp[0] = hv0; hp[64] = hv1; hp[128] = hv2; hp[192] = hv3;
        break;
      }
      PACK(0, hv0) PACK(1, hv1) PACK(2, hv2) PACK(3, hv3)
    }
    __syncthreads();
  }
}

// ---------------- heads + Poincare projection, fp32 out ----------------
__global__ __launch_bounds__(512)
void head2_kernel(const float* __restrict__ HT,
                  const float* __restrict__ muW, const float* __restrict__ mub,
                  const float* __restrict__ lvW, const float* __restrict__ lvb,
                  float* __restrict__ out)
{
  __shared__ float feat[4][512];
  __shared__ float muv[4][64];
  __shared__ float lvv[4][64];
  int tid = threadIdx.x;
  for (int i = tid; i < 2048; i += 512){
    int rr = i >> 8, k = i & 255;
    int b = rr & 3, d = rr >> 2;
    feat[b][d * 256 + k] = HT[i];
  }
  __syncthreads();
  int w = tid >> 6, lane = tid & 63;
  for (int job = w; job < 512; job += 8){
    int j = job & 63, b = (job >> 6) & 3, mat = job >> 8;
    const float* W = (mat ? lvW : muW) + (size_t)j * 512;
    float s = 0.f;
    #pragma unroll
    for (int e = 0; e < 8; ++e) s += W[lane * 8 + e] * feat[b][lane * 8 + e];
    #pragma unroll
    for (int mm = 32; mm >= 1; mm >>= 1) s += __shfl_xor(s, mm);
    if (lane == 0){
      float v = s + (mat ? lvb[j] : mub[j]);
      if (mat) lvv[b][j] = v; else muv[b][j] = v;
    }
  }
  __syncthreads();
  if (tid < 256){
    int b = tid >> 6, j = tid & 63;
    float mu = muv[b][j];
    float sq = mu * mu;
    #pragma unroll
    for (int mm = 32; mm >= 1; mm >>= 1) sq += __shfl_xor(sq, mm);
    float nrm = sqrtf(sq);
    const float mxn = 1.0f - 4e-3f;
    if (nrm > mxn) mu = mu / nrm * mxn;
    out[b * 64 + j] = mu;
    out[256 + b * 64 + j] = lvv[b][j];
  }
}

extern "C" void kernel_launch(void* const* d_in, const int* in_sizes, int n_in,
                              void* d_out, int out_size, void* d_ws, size_t ws_size,
                              hipStream_t stream)
{
  const int* ei = (const int*)d_in[1];

  float* FW   = (float*)d_ws;
  float* Wbuf = FW + FOFF_WBUF;
  int*   csr_row = (int*)(FW + FOFF_CSR);
  unsigned short* csr_src = (unsigned short*)(FW + FOFF_CSR + 132);
  float* XFp  = FW + FOFF_XFP;
  float* XBp  = FW + FOFF_XBP;
  float* HT   = FW + FOFF_HT;
  unsigned short* XSEQ = (unsigned short*)(FW + FOFF_XSEQ);
  unsigned short* PA   = (unsigned short*)(FW + FOFF_PA);
  unsigned short* PB   = (unsigned short*)(FW + FOFF_PB);
  unsigned short* Pb   = (unsigned short*)(FW + FOFF_P);
  unsigned int*   WT   = (unsigned int*)(FW + FOFF_WE);
  unsigned short* BBF  = (unsigned short*)(FW + FOFF_BBF);

  CvtArgs ca;
  static const int wsz[24] = {4096,256,256,256, 65536,256,256,256, 16384,64,64,64,
                              65536,262144,1024,1024, 65536,262144,1024,1024,
                              32768,64,32768,64};
  {
    int acc = 0;
    for (int k = 0; k < 24; ++k){ ca.src[k] = d_in[2 + k]; ca.off[k] = acc; acc += wsz[k]; }
    ca.off[24] = acc;
  }
  int nblk = (SP_TOTAL + 255) / 256 + 1;
  setup_kernel<<<nblk, 256, 0, stream>>>(ca, Wbuf, BBF, Pb, WT,
                                         d_in[0], ei, csr_row, csr_src);

  glayer_kernel<16><<<512, 256, 0, stream>>>(Pb, BBF + BOFF_G0, Wbuf,
                                             WOFF_G0AS, WOFF_G0AD, WOFF_G0B,
                                             csr_row, csr_src, PA);
  glayer_kernel<256><<<512, 256, 0, stream>>>(PA, BBF + BOFF_G1, Wbuf,
                                              WOFF_G1AS, WOFF_G1AD, WOFF_G1B,
                                              csr_row, csr_src, PB);
  glayer2_kernel<<<512, 256, 0, stream>>>(PB, BBF + BOFF_G2, Wbuf,
                                          csr_row, csr_src, XSEQ);

  mmx2_kernel<<<dim3(4, 16, 2), 256, 0, stream>>>(XSEQ, BBF + BOFF_WF, BBF + BOFF_WB,
                                                  Wbuf + WOFF_BIHF, Wbuf + WOFF_BHHF,
                                                  Wbuf + WOFF_BIHB, Wbuf + WOFF_BHHB,
                                                  XFp, XBp, 256, 1024, 64);

  lstm1cu_kernel<<<2, 256, 0, stream>>>(XFp, XBp, WT, HT);

  head2_kernel<<<1, 512, 0, stream>>>(HT, Wbuf + WOFF_MUW, Wbuf + WOFF_MUB,
                                      Wbuf + WOFF_LVW, Wbuf + WOFF_LVB, (float*)d_out);
}

// Round 7
// 345.281 us; speedup vs baseline: 1.8851x; 1.8851x over previous
//
#include <hip/hip_runtime.h>
#include <hip/hip_bf16.h>

// ---- problem constants ----
#define BSZ 4
#define TT 64
#define NNODE 128
#define NFEAT 16
#define HIDD 64
#define NHEAD 4
#define RHID 256
#define LDIM 64
#define EPG 1024
#define NGRAPH (BSZ*TT)          // 256
#define NTOT (NGRAPH*NNODE)      // 32768
#define ESLOTS (EPG+NNODE)       // 1152

// ---- canonical fp32 weight buffer offsets (floats) ----
#define WOFF_G0W 0
#define WOFF_G0AS 4096
#define WOFF_G0AD 4352
#define WOFF_G0B 4608
#define WOFF_G1W 4864
#define WOFF_G1AS 70400
#define WOFF_G1AD 70656
#define WOFF_G1B 70912
#define WOFF_G2W 71168
#define WOFF_G2AS 87552
#define WOFF_G2AD 87616
#define WOFF_G2B 87680
#define WOFF_WIHF 87744
#define WOFF_WHHF 153280
#define WOFF_BIHF 415424
#define WOFF_BHHF 416448
#define WOFF_WIHB 417472
#define WOFF_WHHB 483008
#define WOFF_BIHB 745152
#define WOFF_BHHB 746176
#define WOFF_MUW 747200
#define WOFF_MUB 779968
#define WOFF_LVW 780032
#define WOFF_LVB 812800
#define WTOTAL   812864

// ---- workspace float offsets ----
#define FOFF_WBUF 4096
#define FOFF_CSR  1052672      // csr_row int[132], csr_src u16[1152]
#define FOFF_SYNC 1314816      // HX: 2 dirs x 64 steps x 8 producers x 64 u32 (full rotation, no reset)
#define FOFF_WE   1576960      // WTB (bf16 B-frag Whh, 262144 uints)
#define FOFF_BBF  1900000      // bf16 B matrices (u16 view)
#define FOFF_XFP  2756608
#define FOFF_XBP  3018752
#define FOFF_HT   3280896
#define FOFF_XSEQ 3282944
#define FOFF_PA   3291136      // P0 [32768][256] bf16
#define FOFF_PB   5388288      // P1 [32768][256] bf16
#define FOFF_P    7485440      // X  [32768][16]  bf16

// bf16 B-matrix u16 offsets inside BBF (G0/G1/G2 stored TRANSPOSED [out][in])
#define BOFF_G0 0
#define BOFF_G1 4096
#define BOFF_G2 69632
#define BOFF_WF 86016
#define BOFF_WB 151552
#define BTOTAL  217088

#define LSTM_GRID 16           // 2 dirs x 8 h-quarters (32 h each)
#define HX_WORDS  65536        // 2 x 64 x 512 u32

// setup phases
#define SP_CVTX  (WTOTAL + BTOTAL)            // 1029952
#define SP_WHH   (SP_CVTX + NTOT*NFEAT)       // 1554240
#define SP_HX    (SP_WHH + 262144)            // 1816384
#define SP_TOTAL (SP_HX + HX_WORDS)           // 1881920

#define SENT 0xFFFFFFFFu

typedef __attribute__((ext_vector_type(8))) short short8;
typedef __attribute__((ext_vector_type(4))) float float4v;

__device__ __forceinline__ float b2f(unsigned short u){
  union { unsigned int i; float f; } v; v.i = ((unsigned int)u) << 16; return v.f;
}
__device__ __forceinline__ unsigned short f2b(float f){
  __hip_bfloat16 h = __float2bfloat16(f);
  union { __hip_bfloat16 h; unsigned short u; } v; v.h = h; return v.u;
}
__device__ __forceinline__ float ldf(const void* p, int i, int flag){
  return flag ? b2f(((const unsigned short*)p)[i]) : ((const float*)p)[i];
}
__device__ __forceinline__ float h2f(unsigned short s){
  union { _Float16 hh; unsigned short s; } u; u.s = s; return (float)u.hh;
}
__device__ __forceinline__ unsigned short f2h(float f){
  union { _Float16 hh; unsigned short s; } u; u.hh = (_Float16)f; return u.s;
}
__device__ __forceinline__ int sniff32(const unsigned short* w){
  int ok = 0;
  #pragma unroll
  for (int i = 0; i < 32; ++i){
    float a = fabsf(b2f(w[2 * i]));
    if (a > 1e-8f && a < 4.f) ok++;
  }
  return ok >= 16 ? 1 : 0;
}

// ---------------- fused setup: sniff(once/block) + cvtw + packb(T) + cvtx + packwhh + HX + CSR ----------------
struct CvtArgs {
  const void* src[24];
  int off[25];
};
__global__ void setup_kernel(CvtArgs a,
                             float* __restrict__ W, unsigned short* __restrict__ BBF,
                             unsigned short* __restrict__ P, unsigned int* __restrict__ WT,
                             unsigned int* __restrict__ HX,
                             const void* __restrict__ x, const int* __restrict__ ei,
                             int* __restrict__ csr_row, unsigned short* __restrict__ csr_src)
{
  __shared__ int cnt[NNODE];
  __shared__ int off[NNODE];
  __shared__ int wo[NNODE];
  __shared__ int sfl;
  const int tid = threadIdx.x;

  if (blockIdx.x == gridDim.x - 1){
    if (tid < NNODE) cnt[tid] = 0;
    __syncthreads();
    for (int i = tid; i < ESLOTS; i += 256){
      int d = (i < EPG) ? ei[EPG + i] : (i - EPG);
      atomicAdd(&cnt[d], 1);
    }
    __syncthreads();
    if (tid < NNODE) off[tid] = cnt[tid];
    for (int o = 1; o < NNODE; o <<= 1){
      __syncthreads();
      int t = (tid < NNODE && tid >= o) ? off[tid - o] : 0;
      __syncthreads();
      if (tid < NNODE) off[tid] += t;
    }
    __syncthreads();
    if (tid < NNODE){
      wo[tid] = off[tid] - cnt[tid];
      csr_row[tid + 1] = off[tid];
    }
    if (tid == 0) csr_row[0] = 0;
    __syncthreads();
    for (int i = tid; i < ESLOTS; i += 256){
      int s, d;
      if (i < EPG){ s = ei[i]; d = ei[EPG + i]; } else { s = i - EPG; d = i - EPG; }
      int pos = atomicAdd(&wo[d], 1);
      csr_src[pos] = (unsigned short)s;
    }
    return;
  }

  // sniff ONCE per block (was per-thread: 1.8M x 32 redundant loads)
  if (tid == 0) sfl = sniff32((const unsigned short*)a.src[0]);
  __syncthreads();
  int id = blockIdx.x * blockDim.x + tid;
  if (id >= SP_TOTAL) return;
  const int fl = sfl;

  if (id < WTOTAL){
    int k = 0;
    while (id >= a.off[k + 1]) ++k;
    W[id] = ldf(a.src[k], id - a.off[k], fl);
  } else if (id < WTOTAL + BTOTAL){
    int r = id - WTOTAL;
    float v;
    if (r < BOFF_G1){
      int o = r >> 4, k = r & 15;
      v = ldf(a.src[0], k * 256 + o, fl);
    } else if (r < BOFF_G2){
      int rr = r - BOFF_G1; int o = rr >> 8, k = rr & 255;
      v = ldf(a.src[4], k * 256 + o, fl);
    } else if (r < BOFF_WF){
      int rr = r - BOFF_G2; int o = rr >> 8, k = rr & 255;
      v = ldf(a.src[8], k * 64 + o, fl);
    } else if (r < BOFF_WB){
      int q = r - BOFF_WF; int k = q >> 10, n = q & 1023;
      v = ldf(a.src[12], n * 64 + k, fl);
    } else {
      int q = r - BOFF_WB; int k = q >> 10, n = q & 1023;
      v = ldf(a.src[16], n * 64 + k, fl);
    }
    BBF[r] = f2b(v);
  } else if (id < SP_CVTX + NTOT * NFEAT){
    int r = id - SP_CVTX;
    P[r] = fl ? ((const unsigned short*)x)[r] : f2b(((const float*)x)[r]);
  } else if (id < SP_HX){
    // Whh B-fragment pack for 8-way split: block mm owns gate rows g*256 + 32*mm + [0,32)
    int r0 = id - SP_WHH;
    int c = r0 & 3;
    int lane = (r0 >> 2) & 63;
    int nt = (r0 >> 8) & 7;
    int kc = (r0 >> 11) & 7;
    int mm = (r0 >> 14) & 7;
    int dir = r0 >> 17;
    int l = nt * 16 + (lane & 15);             // [0,128)
    int u = (l >> 5) * 256 + 32 * mm + (l & 31);
    int k0 = kc * 32 + ((lane >> 4) << 3) + 2 * c;
    const void* Wsrc = dir ? a.src[17] : a.src[13];
    unsigned short va = f2b(ldf(Wsrc, u * RHID + k0, fl));
    unsigned short vb = f2b(ldf(Wsrc, u * RHID + k0 + 1, fl));
    WT[r0] = (unsigned int)va | ((unsigned int)vb << 16);
  } else {
    HX[id - SP_HX] = SENT;
  }
}

// ---------------- GAT 4-head half-layer kernel (L0/L1): 512 blocks, MFMA agg, plain stores ----------------
template<int KV>
__global__ __launch_bounds__(256)
void glayer_kernel(const unsigned short* __restrict__ Pin,
                   const unsigned short* __restrict__ BT,
                   const float* __restrict__ Wbuf,
                   int asoff, int adoff, int boff,
                   const int* __restrict__ csr_row, const unsigned short* __restrict__ csr_src,
                   unsigned short* __restrict__ Pout)
{
  __shared__ unsigned short HT_[128 * 136];   // h^T [col][node]
  __shared__ unsigned short AD[128 * 136];    // union: Bst / dense-alpha [dst][src]
  __shared__ unsigned short ALS16[256];
  __shared__ unsigned short ALD16[256];
  __shared__ int   rowL[132];
  __shared__ unsigned char srcL[1152];

  const int tid = threadIdx.x;
  const int g = blockIdx.x >> 1, hb = blockIdx.x & 1;
  const int c0 = hb * 128;
  const int w = tid >> 6, lane = tid & 63, q = lane >> 4, r = lane & 15;
  unsigned short* Bst = AD;

  for (int i = tid; i < 129; i += 256) rowL[i] = csr_row[i];
  for (int i = tid; i < 1152; i += 256) srcL[i] = (unsigned char)csr_src[i];
  __syncthreads();

  // ---- GEMM producing h^T ----
  {
    float4v acc0[8], acc1[8];
    #pragma unroll
    for (int i = 0; i < 8; ++i){ acc0[i] = (float4v){0,0,0,0}; acc1[i] = (float4v){0,0,0,0}; }
    const int KR = (KV + 31) / 32;
    for (int kr = 0; kr < KR; ++kr){
      const int kc = kr * 32;
      __syncthreads();
      {
        int n = tid >> 1, kb = (tid & 1) * 16;
        uint4 z = {0,0,0,0}; uint4 v0 = z, v1 = z;
        if (kb < KV)     v0 = *(const uint4*)(BT + (size_t)(c0 + n) * KV + kc + kb);
        if (kb + 8 < KV) v1 = *(const uint4*)(BT + (size_t)(c0 + n) * KV + kc + kb + 8);
        *(uint4*)&Bst[n * 40 + kb] = v0;
        *(uint4*)&Bst[n * 40 + kb + 8] = v1;
      }
      short8 a0 = {0,0,0,0,0,0,0,0}, a1 = {0,0,0,0,0,0,0,0};
      if (KV >= 32 || q < 2){
        a0 = *(const short8*)(Pin + (size_t)(g * 128 + 16 * w       + r) * KV + kc + q * 8);
        a1 = *(const short8*)(Pin + (size_t)(g * 128 + 16 * (w + 4) + r) * KV + kc + q * 8);
      }
      __syncthreads();
      #pragma unroll
      for (int nt = 0; nt < 8; ++nt){
        short8 bf = *(const short8*)&Bst[(16 * nt + r) * 40 + q * 8];
        acc0[nt] = __builtin_amdgcn_mfma_f32_16x16x32_bf16(a0, bf, acc0[nt], 0, 0, 0);
        acc1[nt] = __builtin_amdgcn_mfma_f32_16x16x32_bf16(a1, bf, acc1[nt], 0, 0, 0);
      }
    }
    __syncthreads();
    #pragma unroll
    for (int nt = 0; nt < 8; ++nt)
      #pragma unroll
      for (int i = 0; i < 4; ++i){
        HT_[(16 * nt + r) * 136 + 16 * w       + q * 4 + i] = f2b(acc0[nt][i]);
        HT_[(16 * nt + r) * 136 + 16 * (w + 4) + q * 4 + i] = f2b(acc1[nt][i]);
      }
    __syncthreads();
  }

  // ---- attention logits (2 local heads) ----
  {
    float as0 = Wbuf[asoff + c0 + 2 * lane], as1 = Wbuf[asoff + c0 + 2 * lane + 1];
    float ad0 = Wbuf[adoff + c0 + 2 * lane], ad1 = Wbuf[adoff + c0 + 2 * lane + 1];
    for (int it = 0; it < 32; ++it){
      int n = it * 4 + w;
      float e0 = b2f(HT_[(2 * lane) * 136 + n]);
      float e1 = b2f(HT_[(2 * lane + 1) * 136 + n]);
      float vs = e0 * as0 + e1 * as1;
      float vd = e0 * ad0 + e1 * ad1;
      #pragma unroll
      for (int m = 16; m >= 1; m >>= 1){ vs += __shfl_xor(vs, m); vd += __shfl_xor(vd, m); }
      if ((lane & 31) == 0){
        ALS16[n * 2 + (lane >> 5)] = f2h(vs);
        ALD16[n * 2 + (lane >> 5)] = f2h(vd);
      }
    }
  }
  __syncthreads();

  // ---- per-head: dense softmax scatter + MFMA agg + plain-store epilogue ----
  for (int hl = 0; hl < 2; ++hl){
    for (int i = tid; i < 8704; i += 256) ((unsigned int*)AD)[i] = 0;
    __syncthreads();
    if (tid < 128){
      int n = tid;
      float aldv = h2f(ALD16[n * 2 + hl]);
      int rs = rowL[n], re = rowL[n + 1];
      float mx = -3e38f, den = 0.f;
      for (int j = rs; j < re; ++j){
        float v = h2f(ALS16[srcL[j] * 2 + hl]) + aldv;
        v = v > 0.f ? v : 0.2f * v;
        if (v > mx){ den = den * __expf(mx - v) + 1.f; mx = v; }
        else den += __expf(v - mx);
      }
      float iden = 1.f / (den + 1e-16f);
      for (int j = rs; j < re; ++j){
        float v = h2f(ALS16[srcL[j] * 2 + hl]) + aldv;
        v = v > 0.f ? v : 0.2f * v;
        float al = __expf(v - mx) * iden;
        int s = srcL[j];
        AD[n * 136 + s] = f2b(b2f(AD[n * 136 + s]) + al);
      }
    }
    __syncthreads();
    float4v am[2][4];
    #pragma unroll
    for (int mt = 0; mt < 2; ++mt)
      #pragma unroll
      for (int nt = 0; nt < 4; ++nt) am[mt][nt] = (float4v){0,0,0,0};
    #pragma unroll
    for (int kc = 0; kc < 4; ++kc){
      short8 af0 = *(const short8*)&AD[(w * 32      + r) * 136 + kc * 32 + q * 8];
      short8 af1 = *(const short8*)&AD[(w * 32 + 16 + r) * 136 + kc * 32 + q * 8];
      #pragma unroll
      for (int nt = 0; nt < 4; ++nt){
        short8 bf = *(const short8*)&HT_[(hl * 64 + nt * 16 + r) * 136 + kc * 32 + q * 8];
        am[0][nt] = __builtin_amdgcn_mfma_f32_16x16x32_bf16(af0, bf, am[0][nt], 0, 0, 0);
        am[1][nt] = __builtin_amdgcn_mfma_f32_16x16x32_bf16(af1, bf, am[1][nt], 0, 0, 0);
      }
    }
    #pragma unroll
    for (int mt = 0; mt < 2; ++mt)
      #pragma unroll
      for (int nt = 0; nt < 4; ++nt){
        int col = hl * 64 + nt * 16 + r;
        float bz = Wbuf[boff + c0 + col];
        #pragma unroll
        for (int i = 0; i < 4; ++i){
          int dst = w * 32 + mt * 16 + q * 4 + i;
          float v = am[mt][nt][i] + bz;
          v = v > 0.f ? v : 0.f;
          Pout[(size_t)(g * 128 + dst) * 256 + c0 + col] = f2b(v);
        }
      }
    __syncthreads();
  }
}

// ---------------- GAT layer 2 (1 head) + pool: 512 blocks ----------------
__global__ __launch_bounds__(256)
void glayer2_kernel(const unsigned short* __restrict__ Pin,
                    const unsigned short* __restrict__ BT,
                    const float* __restrict__ Wbuf,
                    const int* __restrict__ csr_row, const unsigned short* __restrict__ csr_src,
                    unsigned short* __restrict__ XSEQ)
{
  __shared__ unsigned short HT_[64 * 136];
  __shared__ unsigned short AD[128 * 136];
  __shared__ float ALSf[128];
  __shared__ float ALDf[128];
  __shared__ int   rowL[132];
  __shared__ unsigned char srcL[1152];
  __shared__ float pools[4][64];

  const int tid = threadIdx.x;
  const int g = blockIdx.x >> 1, hb = blockIdx.x & 1;
  const int w = tid >> 6, lane = tid & 63, q = lane >> 4, r = lane & 15;
  unsigned short* Bst = AD;

  for (int i = tid; i < 129; i += 256) rowL[i] = csr_row[i];
  for (int i = tid; i < 1152; i += 256) srcL[i] = (unsigned char)csr_src[i];
  __syncthreads();

  // ---- GEMM h2^T [64 cols][128 nodes] ----
  {
    float4v acc0[4], acc1[4];
    #pragma unroll
    for (int i = 0; i < 4; ++i){ acc0[i] = (float4v){0,0,0,0}; acc1[i] = (float4v){0,0,0,0}; }
    for (int kr = 0; kr < 8; ++kr){
      const int kc = kr * 32;
      __syncthreads();
      {
        int n = tid >> 2, kb = (tid & 3) * 8;
        uint4 v = *(const uint4*)(BT + (size_t)n * 256 + kc + kb);
        *(uint4*)&Bst[n * 40 + kb] = v;
      }
      short8 a0 = *(const short8*)(Pin + (size_t)(g * 128 + 16 * w       + r) * 256 + kc + q * 8);
      short8 a1 = *(const short8*)(Pin + (size_t)(g * 128 + 16 * (w + 4) + r) * 256 + kc + q * 8);
      __syncthreads();
      #pragma unroll
      for (int nt = 0; nt < 4; ++nt){
        short8 bf = *(const short8*)&Bst[(16 * nt + r) * 40 + q * 8];
        acc0[nt] = __builtin_amdgcn_mfma_f32_16x16x32_bf16(a0, bf, acc0[nt], 0, 0, 0);
        acc1[nt] = __builtin_amdgcn_mfma_f32_16x16x32_bf16(a1, bf, acc1[nt], 0, 0, 0);
      }
    }
    __syncthreads();
    #pragma unroll
    for (int nt = 0; nt < 4; ++nt)
      #pragma unroll
      for (int i = 0; i < 4; ++i){
        HT_[(16 * nt + r) * 136 + 16 * w       + q * 4 + i] = f2b(acc0[nt][i]);
        HT_[(16 * nt + r) * 136 + 16 * (w + 4) + q * 4 + i] = f2b(acc1[nt][i]);
      }
    __syncthreads();
  }

  // ---- attention (64 cols) ----
  {
    float asv = Wbuf[WOFF_G2AS + lane];
    float adv = Wbuf[WOFF_G2AD + lane];
    for (int it = 0; it < 32; ++it){
      int n = it * 4 + w;
      float e0 = b2f(HT_[lane * 136 + n]);
      float vs = e0 * asv, vd = e0 * adv;
      #pragma unroll
      for (int m = 32; m >= 1; m >>= 1){ vs += __shfl_xor(vs, m); vd += __shfl_xor(vd, m); }
      if (lane == 0){ ALSf[n] = vs; ALDf[n] = vd; }
    }
  }
  __syncthreads();
  for (int i = tid; i < 8704; i += 256) ((unsigned int*)AD)[i] = 0;
  __syncthreads();
  if (tid < 128){
    int n = tid;
    float aldv = ALDf[n];
    int rs = rowL[n], re = rowL[n + 1];
    float mx = -3e38f, den = 0.f;
    for (int j = rs; j < re; ++j){
      float v = ALSf[srcL[j]] + aldv;
      v = v > 0.f ? v : 0.2f * v;
      if (v > mx){ den = den * __expf(mx - v) + 1.f; mx = v; }
      else den += __expf(v - mx);
    }
    float iden = 1.f / (den + 1e-16f);
    for (int j = rs; j < re; ++j){
      float v = ALSf[srcL[j]] + aldv;
      v = v > 0.f ? v : 0.2f * v;
      float al = __expf(v - mx) * iden;
      int s = srcL[j];
      AD[n * 136 + s] = f2b(b2f(AD[n * 136 + s]) + al);
    }
  }
  __syncthreads();
  float4v am[2][4];
  #pragma unroll
  for (int mt = 0; mt < 2; ++mt)
    #pragma unroll
    for (int nt = 0; nt < 4; ++nt) am[mt][nt] = (float4v){0,0,0,0};
  #pragma unroll
  for (int kc = 0; kc < 4; ++kc){
    short8 af0 = *(const short8*)&AD[(w * 32      + r) * 136 + kc * 32 + q * 8];
    short8 af1 = *(const short8*)&AD[(w * 32 + 16 + r) * 136 + kc * 32 + q * 8];
    #pragma unroll
    for (int nt = 0; nt < 4; ++nt){
      short8 bf = *(const short8*)&HT_[(nt * 16 + r) * 136 + kc * 32 + q * 8];
      am[0][nt] = __builtin_amdgcn_mfma_f32_16x16x32_bf16(af0, bf, am[0][nt], 0, 0, 0);
      am[1][nt] = __builtin_amdgcn_mfma_f32_16x16x32_bf16(af1, bf, am[1][nt], 0, 0, 0);
    }
  }
  float psum[4] = {0.f, 0.f, 0.f, 0.f};
  #pragma unroll
  for (int nt = 0; nt < 4; ++nt){
    int col = nt * 16 + r;
    float bz = Wbuf[WOFF_G2B + col];
    #pragma unroll
    for (int mt = 0; mt < 2; ++mt)
      #pragma unroll
      for (int i = 0; i < 4; ++i){
        float v = am[mt][nt][i] + bz;
        psum[nt] += (v > 0.f ? v : 0.f);
      }
    psum[nt] += __shfl_xor(psum[nt], 16);
    psum[nt] += __shfl_xor(psum[nt], 32);
  }
  if (q == 0){
    #pragma unroll
    for (int nt = 0; nt < 4; ++nt) pools[w][nt * 16 + r] = psum[nt];
  }
  __syncthreads();
  if (tid < 64 && (tid >> 5) == hb){
    float s = pools[0][tid] + pools[1][tid] + pools[2][tid] + pools[3][tid];
    int b = g >> 6, tq = g & 63;
    XSEQ[(size_t)(tq * BSZ + b) * HIDD + tid] = f2b(s);
  }
}

// ---------------- MFMA matmul for BOTH Wih GEMMs in one launch (z = dir) ----------------
__global__ __launch_bounds__(256)
void mmx2_kernel(const unsigned short* __restrict__ A,
                 const unsigned short* __restrict__ B0, const unsigned short* __restrict__ B1,
                 float* __restrict__ C0, float* __restrict__ C1, int M, int Nc, int K)
{
  __shared__ unsigned short As[64][40];
  __shared__ unsigned short Bs[64][40];
  const unsigned short* Bb = blockIdx.z ? B1 : B0;
  float* C = blockIdx.z ? C1 : C0;
  const int tid = threadIdx.x;
  const int w = tid >> 6, lane = tid & 63, q = lane >> 4, r = lane & 15;
  const int m0 = blockIdx.x * 64, n0 = blockIdx.y * 64;
  float4v acc0 = {0,0,0,0}, acc1 = {0,0,0,0}, acc2 = {0,0,0,0}, acc3 = {0,0,0,0};
  const int arow = tid >> 2, akb = (tid & 3) * 8;
  const int bk = tid >> 3, bnb = (tid & 7) * 8;
  for (int kc = 0; kc < K; kc += 32){
    int kw = K - kc; if (kw > 32) kw = 32;
    if (akb < kw){
      uint4 v = *(const uint4*)(A + (size_t)(m0 + arow) * K + kc + akb);
      *(uint4*)&As[arow][akb] = v;
    } else {
      uint4 z = {0,0,0,0}; *(uint4*)&As[arow][akb] = z;
    }
    if (bk < kw){
      uint4 v = *(const uint4*)(Bb + (size_t)(kc + bk) * Nc + n0 + bnb);
      const unsigned short* vs = (const unsigned short*)&v;
      #pragma unroll
      for (int e = 0; e < 8; ++e) Bs[bnb + e][bk] = vs[e];
    } else {
      #pragma unroll
      for (int e = 0; e < 8; ++e) Bs[bnb + e][bk] = 0;
    }
    __syncthreads();
    short8 af = *(const short8*)&As[16 * w + r][q * 8];
    short8 b0 = *(const short8*)&Bs[r][q * 8];
    short8 b1 = *(const short8*)&Bs[16 + r][q * 8];
    short8 b2 = *(const short8*)&Bs[32 + r][q * 8];
    short8 b3 = *(const short8*)&Bs[48 + r][q * 8];
    acc0 = __builtin_amdgcn_mfma_f32_16x16x32_bf16(af, b0, acc0, 0, 0, 0);
    acc1 = __builtin_amdgcn_mfma_f32_16x16x32_bf16(af, b1, acc1, 0, 0, 0);
    acc2 = __builtin_amdgcn_mfma_f32_16x16x32_bf16(af, b2, acc2, 0, 0, 0);
    acc3 = __builtin_amdgcn_mfma_f32_16x16x32_bf16(af, b3, acc3, 0, 0, 0);
    __syncthreads();
  }
  const int row = m0 + 16 * w + q * 4, col0 = n0 + r;
  #pragma unroll
  for (int i = 0; i < 4; ++i){
    size_t base = (size_t)(row + i) * Nc;
    C[base + col0]      = acc0[i];
    C[base + col0 + 16] = acc1[i];
    C[base + col0 + 32] = acc2[i];
    C[base + col0 + 48] = acc3[i];
  }
}

// ---------------- LSTM via MFMA: 16 WGs (2 dirs x 8 h-quarters of 32) ----------------
// Full 64-deep HX rotation: producer block mm writes its h quarter ONCE per step to
// HXd + t*512 + mm*64 (u32); consumers poll the 7 partner producer regions directly
// (one u64 poll per thread, 224 threads). No slot reuse within a launch -> no ABA,
// no reset stores. setup re-poisons all slots to SENT each launch (graph-replay safe).
__global__ __launch_bounds__(256)
void lstm13_kernel(const float* __restrict__ XF, const float* __restrict__ XB,
                   const unsigned int* __restrict__ WT,
                   const float* __restrict__ bih_f, const float* __restrict__ bhh_f,
                   const float* __restrict__ bih_b, const float* __restrict__ bhh_b,
                   unsigned int* __restrict__ HX,
                   float* __restrict__ HT)
{
  __shared__ unsigned int WL[16384];          // Whh slice [128 gate rows][256 K] bf16
  __shared__ unsigned int H16[16 * 132];      // full h [16 M-rows][256 K bf16]
  __shared__ float glds[4][128];

  const int tid = threadIdx.x;
  const int mm = blockIdx.x & 7, dir = blockIdx.x >> 3;
  const int w = tid >> 6, lane = tid & 63, quad = lane >> 4, r = lane & 15;
  const float* Xp = dir ? XB : XF;
  unsigned int* HXd = HX + dir * 32768;

  // nonlinearity thread mapping: tid<128 -> (rowb, j)
  const int rowb = tid >> 5, j = tid & 31;    // rowb in [0,8) but only tid<128 used

  const float* bi = dir ? bih_b : bih_f;
  const float* bh = dir ? bhh_b : bhh_f;
  float bias0 = 0.f, bias1 = 0.f, bias2 = 0.f, bias3 = 0.f;
  if (tid < 128){
    bias0 = bi[0 * 256 + 32 * mm + j] + bh[0 * 256 + 32 * mm + j];
    bias1 = bi[1 * 256 + 32 * mm + j] + bh[1 * 256 + 32 * mm + j];
    bias2 = bi[2 * 256 + 32 * mm + j] + bh[2 * 256 + 32 * mm + j];
    bias3 = bi[3 * 256 + 32 * mm + j] + bh[3 * 256 + 32 * mm + j];
  }

  {
    const uint4* WT4 = (const uint4*)(WT + dir * 131072 + mm * 16384);
    uint4* WL4s = (uint4*)WL;
    #pragma unroll
    for (int s = 0; s < 16; ++s)
      WL4s[s * 256 + tid] = WT4[s * 256 + tid];
  }
  for (int i = tid; i < 16 * 132; i += 256) H16[i] = 0;
  float c = 0.f;
  __syncthreads();

  const uint4* WL4 = (const uint4*)WL;
  const uint4* H16u4 = (const uint4*)H16;

  // consumer poll geometry: tid<224 -> partner pl, u64 slot s (b2 rows, pair pp)
  const int pi = tid >> 5;
  const int pl = pi + (pi >= mm ? 1 : 0);
  const int ps = tid & 31, pb2 = ps >> 4, ppp = ps & 15;

  float4v acc[2];
  auto kchunk = [&](int kc){
    uint4 av = H16u4[(lane & 15) * 33 + kc * 4 + quad];
    short8 af = *(const short8*)&av;
    #pragma unroll
    for (int t = 0; t < 2; ++t){
      int nt = w * 2 + t;
      uint4 bv = WL4[(kc * 8 + nt) * 64 + lane];
      short8 bf = *(const short8*)&bv;
      acc[t] = __builtin_amdgcn_mfma_f32_16x16x32_bf16(af, bf, acc[t], 0, 0, 0);
    }
  };

  for (int t = 0; t < TT; ++t){
    const int tb = dir ? (TT - 1 - t) : t;
    float x0 = 0.f, x1 = 0.f, x2 = 0.f, x3 = 0.f;
    if (tid < 128){
      const float* xr = Xp + (size_t)(tb * 4 + rowb) * 1024 + 32 * mm + j;
      x0 = xr[0]; x1 = xr[256]; x2 = xr[512]; x3 = xr[768];
    }

    acc[0] = (float4v){0,0,0,0}; acc[1] = (float4v){0,0,0,0};
    kchunk(mm);                                  // own K-chunk overlaps the poll
    if (t > 0 && tid < 224){
      const unsigned long long* pg =
        (const unsigned long long*)(HXd + (size_t)(t - 1) * 512 + pl * 64) + ps;
      unsigned long long pv;
      int guard = 0;
      for (;;){
        pv = __hip_atomic_load(pg, __ATOMIC_RELAXED, __HIP_MEMORY_SCOPE_AGENT);
        if (((unsigned int)pv != SENT) && ((unsigned int)(pv >> 32) != SENT)) break;
        if (++guard >= 200000) break;
      }
      H16[pb2 * 132 + 16 * pl + ppp]       = (unsigned int)pv;
      H16[(pb2 + 2) * 132 + 16 * pl + ppp] = (unsigned int)(pv >> 32);
    }
    __syncthreads();
    #pragma unroll
    for (int i = 1; i < 8; ++i)
      kchunk((mm + i) & 7);
    if (quad == 0){
      #pragma unroll
      for (int tt = 0; tt < 2; ++tt){
        int l = (w * 2 + tt) * 16 + r;
        glds[0][l] = acc[tt][0];
        glds[1][l] = acc[tt][1];
        glds[2][l] = acc[tt][2];
        glds[3][l] = acc[tt][3];
      }
    }
    __syncthreads();

    if (tid < 128){
      float gi = glds[rowb][j]      + bias0 + x0;
      float gf = glds[rowb][32 + j] + bias1 + x1;
      float gg = glds[rowb][64 + j] + bias2 + x2;
      float go = glds[rowb][96 + j] + bias3 + x3;
      float si = 1.f / (1.f + __expf(-gi));
      float sf = 1.f / (1.f + __expf(-gf));
      float so = 1.f / (1.f + __expf(-go));
      float tg = 1.f - 2.f / (1.f + __expf(2.f * gg));
      c = sf * c + si * tg;
      float ch = 1.f - 2.f / (1.f + __expf(2.f * c));
      float hval = so * ch;
      if (t == TT - 1){
        HT[(size_t)(dir * 4 + rowb) * RHID + (32 * mm + j)] = hval;
      } else {
        unsigned int own = f2b(hval);
        unsigned int partner = ((unsigned int)__shfl_xor((int)own, 1)) & 0xffffu;
        if ((j & 1) == 0){
          unsigned int v = own | (partner << 16);
          // u32 slot: rows (b2, b2+2) paired into u64s; this thread writes its half
          int u32off = ((rowb & 1) * 16 + (j >> 1)) * 2 + (rowb >> 1);
          H16[rowb * 132 + 16 * mm + (j >> 1)] = v;
          __hip_atomic_store(HXd + (size_t)t * 512 + mm * 64 + u32off, v,
                             __ATOMIC_RELAXED, __HIP_MEMORY_SCOPE_AGENT);
        }
      }
    }
    if (t == TT - 1) break;
    __syncthreads();
  }
}

// ---------------- heads + Poincare projection, fp32 out ----------------
__global__ __launch_bounds__(512)
void head2_kernel(const float* __restrict__ HT,
                  const float* __restrict__ muW, const float* __restrict__ mub,
                  const float* __restrict__ lvW, const float* __restrict__ lvb,
                  float* __restrict__ out)
{
  __shared__ float feat[4][512];
  __shared__ float muv[4][64];
  __shared__ float lvv[4][64];
  int tid = threadIdx.x;
  for (int i = tid; i < 2048; i += 512){
    int rr = i >> 8, k = i & 255;
    int b = rr & 3, d = rr >> 2;
    feat[b][d * 256 + k] = HT[i];
  }
  __syncthreads();
  int w = tid >> 6, lane = tid & 63;
  for (int job = w; job < 512; job += 8){
    int j = job & 63, b = (job >> 6) & 3, mat = job >> 8;
    const float* W = (mat ? lvW : muW) + (size_t)j * 512;
    float s = 0.f;
    #pragma unroll
    for (int e = 0; e < 8; ++e) s += W[lane * 8 + e] * feat[b][lane * 8 + e];
    #pragma unroll
    for (int mm = 32; mm >= 1; mm >>= 1) s += __shfl_xor(s, mm);
    if (lane == 0){
      float v = s + (mat ? lvb[j] : mub[j]);
      if (mat) lvv[b][j] = v; else muv[b][j] = v;
    }
  }
  __syncthreads();
  if (tid < 256){
    int b = tid >> 6, j = tid & 63;
    float mu = muv[b][j];
    float sq = mu * mu;
    #pragma unroll
    for (int mm = 32; mm >= 1; mm >>= 1) sq += __shfl_xor(sq, mm);
    float nrm = sqrtf(sq);
    const float mxn = 1.0f - 4e-3f;
    if (nrm > mxn) mu = mu / nrm * mxn;
    out[b * 64 + j] = mu;
    out[256 + b * 64 + j] = lvv[b][j];
  }
}

extern "C" void kernel_launch(void* const* d_in, const int* in_sizes, int n_in,
                              void* d_out, int out_size, void* d_ws, size_t ws_size,
                              hipStream_t stream)
{
  const int* ei = (const int*)d_in[1];

  float* FW   = (float*)d_ws;
  float* Wbuf = FW + FOFF_WBUF;
  int*   csr_row = (int*)(FW + FOFF_CSR);
  unsigned short* csr_src = (unsigned short*)(FW + FOFF_CSR + 132);
  float* XFp  = FW + FOFF_XFP;
  float* XBp  = FW + FOFF_XBP;
  float* HT   = FW + FOFF_HT;
  unsigned short* XSEQ = (unsigned short*)(FW + FOFF_XSEQ);
  unsigned short* PA   = (unsigned short*)(FW + FOFF_PA);
  unsigned short* PB   = (unsigned short*)(FW + FOFF_PB);
  unsigned short* Pb   = (unsigned short*)(FW + FOFF_P);
  unsigned int*   WT   = (unsigned int*)(FW + FOFF_WE);
  unsigned short* BBF  = (unsigned short*)(FW + FOFF_BBF);
  unsigned int*   HX   = (unsigned int*)(FW + FOFF_SYNC);

  CvtArgs ca;
  static const int wsz[24] = {4096,256,256,256, 65536,256,256,256, 16384,64,64,64,
                              65536,262144,1024,1024, 65536,262144,1024,1024,
                              32768,64,32768,64};
  {
    int acc = 0;
    for (int k = 0; k < 24; ++k){ ca.src[k] = d_in[2 + k]; ca.off[k] = acc; acc += wsz[k]; }
    ca.off[24] = acc;
  }
  int nblk = (SP_TOTAL + 255) / 256 + 1;
  setup_kernel<<<nblk, 256, 0, stream>>>(ca, Wbuf, BBF, Pb, WT, HX,
                                         d_in[0], ei, csr_row, csr_src);

  glayer_kernel<16><<<512, 256, 0, stream>>>(Pb, BBF + BOFF_G0, Wbuf,
                                             WOFF_G0AS, WOFF_G0AD, WOFF_G0B,
                                             csr_row, csr_src, PA);
  glayer_kernel<256><<<512, 256, 0, stream>>>(PA, BBF + BOFF_G1, Wbuf,
                                              WOFF_G1AS, WOFF_G1AD, WOFF_G1B,
                                              csr_row, csr_src, PB);
  glayer2_kernel<<<512, 256, 0, stream>>>(PB, BBF + BOFF_G2, Wbuf,
                                          csr_row, csr_src, XSEQ);

  mmx2_kernel<<<dim3(4, 16, 2), 256, 0, stream>>>(XSEQ, BBF + BOFF_WF, BBF + BOFF_WB,
                                                  XFp, XBp, 256, 1024, 64);

  lstm13_kernel<<<LSTM_GRID, 256, 0, stream>>>(XFp, XBp, WT,
                                               Wbuf + WOFF_BIHF, Wbuf + WOFF_BHHF,
                                               Wbuf + WOFF_BIHB, Wbuf + WOFF_BHHB,
                                               HX, HT);

  head2_kernel<<<1, 512, 0, stream>>>(HT, Wbuf + WOFF_MUW, Wbuf + WOFF_MUB,
                                      Wbuf + WOFF_LVW, Wbuf + WOFF_LVB, (float*)d_out);
}

// Round 8
// 317.165 us; speedup vs baseline: 2.0522x; 1.0886x over previous
//
#include <hip/hip_runtime.h>
#include <hip/hip_bf16.h>

// ---- problem constants ----
#define BSZ 4
#define TT 64
#define NNODE 128
#define NFEAT 16
#define HIDD 64
#define NHEAD 4
#define RHID 256
#define LDIM 64
#define EPG 1024
#define NGRAPH (BSZ*TT)          // 256
#define NTOT (NGRAPH*NNODE)      // 32768
#define ESLOTS (EPG+NNODE)       // 1152

// ---- canonical fp32 weight buffer offsets (floats) ----
#define WOFF_G0W 0
#define WOFF_G0AS 4096
#define WOFF_G0AD 4352
#define WOFF_G0B 4608
#define WOFF_G1W 4864
#define WOFF_G1AS 70400
#define WOFF_G1AD 70656
#define WOFF_G1B 70912
#define WOFF_G2W 71168
#define WOFF_G2AS 87552
#define WOFF_G2AD 87616
#define WOFF_G2B 87680
#define WOFF_WIHF 87744
#define WOFF_WHHF 153280
#define WOFF_BIHF 415424
#define WOFF_BHHF 416448
#define WOFF_WIHB 417472
#define WOFF_WHHB 483008
#define WOFF_BIHB 745152
#define WOFF_BHHB 746176
#define WOFF_MUW 747200
#define WOFF_MUB 779968
#define WOFF_LVW 780032
#define WOFF_LVB 812800
#define WTOTAL   812864

// ---- workspace float offsets ----
#define FOFF_WBUF 4096
#define FOFF_CSR  1052672      // csr_row int[132], csr_src u16[1152]
#define FOFF_SYNC 1314816      // HX: 2 dirs x 64 steps x 8 producers x 64 u32 (full rotation, no reset)
#define FOFF_WE   1576960      // WTB (bf16 B-frag Whh, 262144 uints)
#define FOFF_BBF  1900000      // bf16 B matrices (u16 view)
#define FOFF_XFP  2756608
#define FOFF_XBP  3018752
#define FOFF_HT   3280896
#define FOFF_XSEQ 3282944
#define FOFF_PA   3291136      // P0 [32768][256] bf16
#define FOFF_PB   5388288      // P1 [32768][256] bf16
#define FOFF_P    7485440      // X  [32768][16]  bf16

// bf16 B-matrix u16 offsets inside BBF (G0/G1/G2 stored TRANSPOSED [out][in])
#define BOFF_G0 0
#define BOFF_G1 4096
#define BOFF_G2 69632
#define BOFF_WF 86016
#define BOFF_WB 151552
#define BTOTAL  217088

#define LSTM_GRID 16           // 2 dirs x 8 h-quarters (32 h each)
#define HX_WORDS  65536        // 2 x 64 x 512 u32

// setup phases
#define SP_CVTX  (WTOTAL + BTOTAL)            // 1029952
#define SP_WHH   (SP_CVTX + NTOT*NFEAT)       // 1554240
#define SP_HX    (SP_WHH + 262144)            // 1816384
#define SP_TOTAL (SP_HX + HX_WORDS)           // 1881920

#define SENT 0xFFFFFFFFu

typedef __attribute__((ext_vector_type(8))) short short8;
typedef __attribute__((ext_vector_type(4))) float float4v;

__device__ __forceinline__ float b2f(unsigned short u){
  union { unsigned int i; float f; } v; v.i = ((unsigned int)u) << 16; return v.f;
}
__device__ __forceinline__ unsigned short f2b(float f){
  __hip_bfloat16 h = __float2bfloat16(f);
  union { __hip_bfloat16 h; unsigned short u; } v; v.h = h; return v.u;
}
__device__ __forceinline__ float ldf(const void* p, int i, int flag){
  return flag ? b2f(((const unsigned short*)p)[i]) : ((const float*)p)[i];
}
__device__ __forceinline__ float h2f(unsigned short s){
  union { _Float16 hh; unsigned short s; } u; u.s = s; return (float)u.hh;
}
__device__ __forceinline__ unsigned short f2h(float f){
  union { _Float16 hh; unsigned short s; } u; u.hh = (_Float16)f; return u.s;
}
__device__ __forceinline__ int sniff32(const unsigned short* w){
  int ok = 0;
  #pragma unroll
  for (int i = 0; i < 32; ++i){
    float a = fabsf(b2f(w[2 * i]));
    if (a > 1e-8f && a < 4.f) ok++;
  }
  return ok >= 16 ? 1 : 0;
}

// ---------------- fused setup: sniff(once/block) + cvtw + packb(T) + cvtx + packwhh + HX + CSR ----------------
struct CvtArgs {
  const void* src[24];
  int off[25];
};
__global__ void setup_kernel(CvtArgs a,
                             float* __restrict__ W, unsigned short* __restrict__ BBF,
                             unsigned short* __restrict__ P, unsigned int* __restrict__ WT,
                             unsigned int* __restrict__ HX,
                             const void* __restrict__ x, const int* __restrict__ ei,
                             int* __restrict__ csr_row, unsigned short* __restrict__ csr_src)
{
  __shared__ int cnt[NNODE];
  __shared__ int off[NNODE];
  __shared__ int wo[NNODE];
  __shared__ int sfl;
  const int tid = threadIdx.x;

  if (blockIdx.x == gridDim.x - 1){
    if (tid < NNODE) cnt[tid] = 0;
    __syncthreads();
    for (int i = tid; i < ESLOTS; i += 256){
      int d = (i < EPG) ? ei[EPG + i] : (i - EPG);
      atomicAdd(&cnt[d], 1);
    }
    __syncthreads();
    if (tid < NNODE) off[tid] = cnt[tid];
    for (int o = 1; o < NNODE; o <<= 1){
      __syncthreads();
      int t = (tid < NNODE && tid >= o) ? off[tid - o] : 0;
      __syncthreads();
      if (tid < NNODE) off[tid] += t;
    }
    __syncthreads();
    if (tid < NNODE){
      wo[tid] = off[tid] - cnt[tid];
      csr_row[tid + 1] = off[tid];
    }
    if (tid == 0) csr_row[0] = 0;
    __syncthreads();
    for (int i = tid; i < ESLOTS; i += 256){
      int s, d;
      if (i < EPG){ s = ei[i]; d = ei[EPG + i]; } else { s = i - EPG; d = i - EPG; }
      int pos = atomicAdd(&wo[d], 1);
      csr_src[pos] = (unsigned short)s;
    }
    return;
  }

  // sniff ONCE per block (was per-thread: 1.8M x 32 redundant loads)
  if (tid == 0) sfl = sniff32((const unsigned short*)a.src[0]);
  __syncthreads();
  int id = blockIdx.x * blockDim.x + tid;
  if (id >= SP_TOTAL) return;
  const int fl = sfl;

  if (id < WTOTAL){
    int k = 0;
    while (id >= a.off[k + 1]) ++k;
    W[id] = ldf(a.src[k], id - a.off[k], fl);
  } else if (id < WTOTAL + BTOTAL){
    int r = id - WTOTAL;
    float v;
    if (r < BOFF_G1){
      int o = r >> 4, k = r & 15;
      v = ldf(a.src[0], k * 256 + o, fl);
    } else if (r < BOFF_G2){
      int rr = r - BOFF_G1; int o = rr >> 8, k = rr & 255;
      v = ldf(a.src[4], k * 256 + o, fl);
    } else if (r < BOFF_WF){
      int rr = r - BOFF_G2; int o = rr >> 8, k = rr & 255;
      v = ldf(a.src[8], k * 64 + o, fl);
    } else if (r < BOFF_WB){
      int q = r - BOFF_WF; int k = q >> 10, n = q & 1023;
      v = ldf(a.src[12], n * 64 + k, fl);
    } else {
      int q = r - BOFF_WB; int k = q >> 10, n = q & 1023;
      v = ldf(a.src[16], n * 64 + k, fl);
    }
    BBF[r] = f2b(v);
  } else if (id < SP_CVTX + NTOT * NFEAT){
    int r = id - SP_CVTX;
    P[r] = fl ? ((const unsigned short*)x)[r] : f2b(((const float*)x)[r]);
  } else if (id < SP_HX){
    // Whh B-fragment pack for 8-way split: block mm owns gate rows g*256 + 32*mm + [0,32)
    int r0 = id - SP_WHH;
    int c = r0 & 3;
    int lane = (r0 >> 2) & 63;
    int nt = (r0 >> 8) & 7;
    int kc = (r0 >> 11) & 7;
    int mm = (r0 >> 14) & 7;
    int dir = r0 >> 17;
    int l = nt * 16 + (lane & 15);             // [0,128)
    int u = (l >> 5) * 256 + 32 * mm + (l & 31);
    int k0 = kc * 32 + ((lane >> 4) << 3) + 2 * c;
    const void* Wsrc = dir ? a.src[17] : a.src[13];
    unsigned short va = f2b(ldf(Wsrc, u * RHID + k0, fl));
    unsigned short vb = f2b(ldf(Wsrc, u * RHID + k0 + 1, fl));
    WT[r0] = (unsigned int)va | ((unsigned int)vb << 16);
  } else {
    HX[id - SP_HX] = SENT;
  }
}

// ---------------- GAT 4-head half-layer kernel (L0/L1): 512 blocks, MFMA agg ----------------
// r8: (1) logits via per-thread column dot (no shfl chains; a_src/a_dst staged in LDS);
//     (2) B-tile software prefetch hides global latency under MFMA.
template<int KV>
__global__ __launch_bounds__(256)
void glayer_kernel(const unsigned short* __restrict__ Pin,
                   const unsigned short* __restrict__ BT,
                   const float* __restrict__ Wbuf,
                   int asoff, int adoff, int boff,
                   const int* __restrict__ csr_row, const unsigned short* __restrict__ csr_src,
                   unsigned short* __restrict__ Pout)
{
  __shared__ unsigned short HT_[128 * 136];   // h^T [col][node]
  __shared__ unsigned short AD[128 * 136];    // union: Bst / dense-alpha [dst][src]
  __shared__ unsigned short ALS16[256];
  __shared__ unsigned short ALD16[256];
  __shared__ float ASL[128];
  __shared__ float ADL[128];
  __shared__ int   rowL[132];
  __shared__ unsigned char srcL[1152];

  const int tid = threadIdx.x;
  const int g = blockIdx.x >> 1, hb = blockIdx.x & 1;
  const int c0 = hb * 128;
  const int w = tid >> 6, lane = tid & 63, q = lane >> 4, r = lane & 15;
  unsigned short* Bst = AD;

  for (int i = tid; i < 129; i += 256) rowL[i] = csr_row[i];
  for (int i = tid; i < 1152; i += 256) srcL[i] = (unsigned char)csr_src[i];
  if (tid < 128){
    ASL[tid] = Wbuf[asoff + c0 + tid];
    ADL[tid] = Wbuf[adoff + c0 + tid];
  }
  __syncthreads();

  // ---- GEMM producing h^T (B prefetched one iter ahead) ----
  {
    float4v acc0[8], acc1[8];
    #pragma unroll
    for (int i = 0; i < 8; ++i){ acc0[i] = (float4v){0,0,0,0}; acc1[i] = (float4v){0,0,0,0}; }
    const int KR = (KV + 31) / 32;
    const int bn = tid >> 1, bkb = (tid & 1) * 16;
    uint4 z = {0,0,0,0};
    uint4 vb0 = z, vb1 = z;
    if (bkb < KV)     vb0 = *(const uint4*)(BT + (size_t)(c0 + bn) * KV + bkb);
    if (bkb + 8 < KV) vb1 = *(const uint4*)(BT + (size_t)(c0 + bn) * KV + bkb + 8);
    for (int kr = 0; kr < KR; ++kr){
      const int kc = kr * 32;
      __syncthreads();
      *(uint4*)&Bst[bn * 40 + bkb] = vb0;
      *(uint4*)&Bst[bn * 40 + bkb + 8] = vb1;
      short8 a0 = {0,0,0,0,0,0,0,0}, a1 = {0,0,0,0,0,0,0,0};
      if (KV >= 32 || q < 2){
        a0 = *(const short8*)(Pin + (size_t)(g * 128 + 16 * w       + r) * KV + kc + q * 8);
        a1 = *(const short8*)(Pin + (size_t)(g * 128 + 16 * (w + 4) + r) * KV + kc + q * 8);
      }
      __syncthreads();
      if (kr + 1 < KR){
        const int kc2 = kc + 32;
        if (bkb < KV)     vb0 = *(const uint4*)(BT + (size_t)(c0 + bn) * KV + kc2 + bkb);
        if (bkb + 8 < KV) vb1 = *(const uint4*)(BT + (size_t)(c0 + bn) * KV + kc2 + bkb + 8);
      }
      #pragma unroll
      for (int nt = 0; nt < 8; ++nt){
        short8 bf = *(const short8*)&Bst[(16 * nt + r) * 40 + q * 8];
        acc0[nt] = __builtin_amdgcn_mfma_f32_16x16x32_bf16(a0, bf, acc0[nt], 0, 0, 0);
        acc1[nt] = __builtin_amdgcn_mfma_f32_16x16x32_bf16(a1, bf, acc1[nt], 0, 0, 0);
      }
    }
    __syncthreads();
    #pragma unroll
    for (int nt = 0; nt < 8; ++nt)
      #pragma unroll
      for (int i = 0; i < 4; ++i){
        HT_[(16 * nt + r) * 136 + 16 * w       + q * 4 + i] = f2b(acc0[nt][i]);
        HT_[(16 * nt + r) * 136 + 16 * (w + 4) + q * 4 + i] = f2b(acc1[nt][i]);
      }
    __syncthreads();
  }

  // ---- attention logits: thread (n, hl) dots h^T column n over its head's 64 cols ----
  {
    const int n = tid & 127, hl = tid >> 7;
    const int cb = hl * 64;
    float vs = 0.f, vd = 0.f;
    #pragma unroll 8
    for (int c = 0; c < 64; ++c){
      float e = b2f(HT_[(cb + c) * 136 + n]);
      vs += e * ASL[cb + c];
      vd += e * ADL[cb + c];
    }
    ALS16[n * 2 + hl] = f2h(vs);
    ALD16[n * 2 + hl] = f2h(vd);
  }
  __syncthreads();

  // ---- per-head: dense softmax scatter + MFMA agg + plain-store epilogue ----
  for (int hl = 0; hl < 2; ++hl){
    for (int i = tid; i < 8704; i += 256) ((unsigned int*)AD)[i] = 0;
    __syncthreads();
    if (tid < 128){
      int n = tid;
      float aldv = h2f(ALD16[n * 2 + hl]);
      int rs = rowL[n], re = rowL[n + 1];
      float mx = -3e38f, den = 0.f;
      for (int j = rs; j < re; ++j){
        float v = h2f(ALS16[srcL[j] * 2 + hl]) + aldv;
        v = v > 0.f ? v : 0.2f * v;
        if (v > mx){ den = den * __expf(mx - v) + 1.f; mx = v; }
        else den += __expf(v - mx);
      }
      float iden = 1.f / (den + 1e-16f);
      for (int j = rs; j < re; ++j){
        float v = h2f(ALS16[srcL[j] * 2 + hl]) + aldv;
        v = v > 0.f ? v : 0.2f * v;
        float al = __expf(v - mx) * iden;
        int s = srcL[j];
        AD[n * 136 + s] = f2b(b2f(AD[n * 136 + s]) + al);
      }
    }
    __syncthreads();
    float4v am[2][4];
    #pragma unroll
    for (int mt = 0; mt < 2; ++mt)
      #pragma unroll
      for (int nt = 0; nt < 4; ++nt) am[mt][nt] = (float4v){0,0,0,0};
    #pragma unroll
    for (int kc = 0; kc < 4; ++kc){
      short8 af0 = *(const short8*)&AD[(w * 32      + r) * 136 + kc * 32 + q * 8];
      short8 af1 = *(const short8*)&AD[(w * 32 + 16 + r) * 136 + kc * 32 + q * 8];
      #pragma unroll
      for (int nt = 0; nt < 4; ++nt){
        short8 bf = *(const short8*)&HT_[(hl * 64 + nt * 16 + r) * 136 + kc * 32 + q * 8];
        am[0][nt] = __builtin_amdgcn_mfma_f32_16x16x32_bf16(af0, bf, am[0][nt], 0, 0, 0);
        am[1][nt] = __builtin_amdgcn_mfma_f32_16x16x32_bf16(af1, bf, am[1][nt], 0, 0, 0);
      }
    }
    #pragma unroll
    for (int mt = 0; mt < 2; ++mt)
      #pragma unroll
      for (int nt = 0; nt < 4; ++nt){
        int col = hl * 64 + nt * 16 + r;
        float bz = Wbuf[boff + c0 + col];
        #pragma unroll
        for (int i = 0; i < 4; ++i){
          int dst = w * 32 + mt * 16 + q * 4 + i;
          float v = am[mt][nt][i] + bz;
          v = v > 0.f ? v : 0.f;
          Pout[(size_t)(g * 128 + dst) * 256 + c0 + col] = f2b(v);
        }
      }
    __syncthreads();
  }
}

// ---------------- GAT layer 2 (1 head) + pool: 512 blocks ----------------
__global__ __launch_bounds__(256)
void glayer2_kernel(const unsigned short* __restrict__ Pin,
                    const unsigned short* __restrict__ BT,
                    const float* __restrict__ Wbuf,
                    const int* __restrict__ csr_row, const unsigned short* __restrict__ csr_src,
                    unsigned short* __restrict__ XSEQ)
{
  __shared__ unsigned short HT_[64 * 136];
  __shared__ unsigned short AD[128 * 136];
  __shared__ float ALSf[128];
  __shared__ float ALDf[128];
  __shared__ float ASL2[64];
  __shared__ float ADL2[64];
  __shared__ int   rowL[132];
  __shared__ unsigned char srcL[1152];
  __shared__ float pools[4][64];

  const int tid = threadIdx.x;
  const int g = blockIdx.x >> 1, hb = blockIdx.x & 1;
  const int w = tid >> 6, lane = tid & 63, q = lane >> 4, r = lane & 15;
  unsigned short* Bst = AD;

  for (int i = tid; i < 129; i += 256) rowL[i] = csr_row[i];
  for (int i = tid; i < 1152; i += 256) srcL[i] = (unsigned char)csr_src[i];
  if (tid < 64){
    ASL2[tid] = Wbuf[WOFF_G2AS + tid];
    ADL2[tid] = Wbuf[WOFF_G2AD + tid];
  }
  __syncthreads();

  // ---- GEMM h2^T [64 cols][128 nodes] (B prefetched one iter ahead) ----
  {
    float4v acc0[4], acc1[4];
    #pragma unroll
    for (int i = 0; i < 4; ++i){ acc0[i] = (float4v){0,0,0,0}; acc1[i] = (float4v){0,0,0,0}; }
    const int bn = tid >> 2, bkb = (tid & 3) * 8;
    uint4 vb = *(const uint4*)(BT + (size_t)bn * 256 + bkb);
    for (int kr = 0; kr < 8; ++kr){
      const int kc = kr * 32;
      __syncthreads();
      *(uint4*)&Bst[bn * 40 + bkb] = vb;
      short8 a0 = *(const short8*)(Pin + (size_t)(g * 128 + 16 * w       + r) * 256 + kc + q * 8);
      short8 a1 = *(const short8*)(Pin + (size_t)(g * 128 + 16 * (w + 4) + r) * 256 + kc + q * 8);
      __syncthreads();
      if (kr < 7)
        vb = *(const uint4*)(BT + (size_t)bn * 256 + kc + 32 + bkb);
      #pragma unroll
      for (int nt = 0; nt < 4; ++nt){
        short8 bf = *(const short8*)&Bst[(16 * nt + r) * 40 + q * 8];
        acc0[nt] = __builtin_amdgcn_mfma_f32_16x16x32_bf16(a0, bf, acc0[nt], 0, 0, 0);
        acc1[nt] = __builtin_amdgcn_mfma_f32_16x16x32_bf16(a1, bf, acc1[nt], 0, 0, 0);
      }
    }
    __syncthreads();
    #pragma unroll
    for (int nt = 0; nt < 4; ++nt)
      #pragma unroll
      for (int i = 0; i < 4; ++i){
        HT_[(16 * nt + r) * 136 + 16 * w       + q * 4 + i] = f2b(acc0[nt][i]);
        HT_[(16 * nt + r) * 136 + 16 * (w + 4) + q * 4 + i] = f2b(acc1[nt][i]);
      }
    __syncthreads();
  }

  // ---- attention logits: thread n dots h2^T column n over 64 cols ----
  if (tid < 128){
    const int n = tid;
    float vs = 0.f, vd = 0.f;
    #pragma unroll 8
    for (int c = 0; c < 64; ++c){
      float e = b2f(HT_[c * 136 + n]);
      vs += e * ASL2[c];
      vd += e * ADL2[c];
    }
    ALSf[n] = vs;
    ALDf[n] = vd;
  }
  __syncthreads();
  for (int i = tid; i < 8704; i += 256) ((unsigned int*)AD)[i] = 0;
  __syncthreads();
  if (tid < 128){
    int n = tid;
    float aldv = ALDf[n];
    int rs = rowL[n], re = rowL[n + 1];
    float mx = -3e38f, den = 0.f;
    for (int j = rs; j < re; ++j){
      float v = ALSf[srcL[j]] + aldv;
      v = v > 0.f ? v : 0.2f * v;
      if (v > mx){ den = den * __expf(mx - v) + 1.f; mx = v; }
      else den += __expf(v - mx);
    }
    float iden = 1.f / (den + 1e-16f);
    for (int j = rs; j < re; ++j){
      float v = ALSf[srcL[j]] + aldv;
      v = v > 0.f ? v : 0.2f * v;
      float al = __expf(v - mx) * iden;
      int s = srcL[j];
      AD[n * 136 + s] = f2b(b2f(AD[n * 136 + s]) + al);
    }
  }
  __syncthreads();
  float4v am[2][4];
  #pragma unroll
  for (int mt = 0; mt < 2; ++mt)
    #pragma unroll
    for (int nt = 0; nt < 4; ++nt) am[mt][nt] = (float4v){0,0,0,0};
  #pragma unroll
  for (int kc = 0; kc < 4; ++kc){
    short8 af0 = *(const short8*)&AD[(w * 32      + r) * 136 + kc * 32 + q * 8];
    short8 af1 = *(const short8*)&AD[(w * 32 + 16 + r) * 136 + kc * 32 + q * 8];
    #pragma unroll
    for (int nt = 0; nt < 4; ++nt){
      short8 bf = *(const short8*)&HT_[(nt * 16 + r) * 136 + kc * 32 + q * 8];
      am[0][nt] = __builtin_amdgcn_mfma_f32_16x16x32_bf16(af0, bf, am[0][nt], 0, 0, 0);
      am[1][nt] = __builtin_amdgcn_mfma_f32_16x16x32_bf16(af1, bf, am[1][nt], 0, 0, 0);
    }
  }
  float psum[4] = {0.f, 0.f, 0.f, 0.f};
  #pragma unroll
  for (int nt = 0; nt < 4; ++nt){
    int col = nt * 16 + r;
    float bz = Wbuf[WOFF_G2B + col];
    #pragma unroll
    for (int mt = 0; mt < 2; ++mt)
      #pragma unroll
      for (int i = 0; i < 4; ++i){
        float v = am[mt][nt][i] + bz;
        psum[nt] += (v > 0.f ? v : 0.f);
      }
    psum[nt] += __shfl_xor(psum[nt], 16);
    psum[nt] += __shfl_xor(psum[nt], 32);
  }
  if (q == 0){
    #pragma unroll
    for (int nt = 0; nt < 4; ++nt) pools[w][nt * 16 + r] = psum[nt];
  }
  __syncthreads();
  if (tid < 64 && (tid >> 5) == hb){
    float s = pools[0][tid] + pools[1][tid] + pools[2][tid] + pools[3][tid];
    int b = g >> 6, tq = g & 63;
    XSEQ[(size_t)(tq * BSZ + b) * HIDD + tid] = f2b(s);
  }
}

// ---------------- MFMA matmul for BOTH Wih GEMMs in one launch (z = dir) ----------------
__global__ __launch_bounds__(256)
void mmx2_kernel(const unsigned short* __restrict__ A,
                 const unsigned short* __restrict__ B0, const unsigned short* __restrict__ B1,
                 float* __restrict__ C0, float* __restrict__ C1, int M, int Nc, int K)
{
  __shared__ unsigned short As[64][40];
  __shared__ unsigned short Bs[64][40];
  const unsigned short* Bb = blockIdx.z ? B1 : B0;
  float* C = blockIdx.z ? C1 : C0;
  const int tid = threadIdx.x;
  const int w = tid >> 6, lane = tid & 63, q = lane >> 4, r = lane & 15;
  const int m0 = blockIdx.x * 64, n0 = blockIdx.y * 64;
  float4v acc0 = {0,0,0,0}, acc1 = {0,0,0,0}, acc2 = {0,0,0,0}, acc3 = {0,0,0,0};
  const int arow = tid >> 2, akb = (tid & 3) * 8;
  const int bk = tid >> 3, bnb = (tid & 7) * 8;
  for (int kc = 0; kc < K; kc += 32){
    int kw = K - kc; if (kw > 32) kw = 32;
    if (akb < kw){
      uint4 v = *(const uint4*)(A + (size_t)(m0 + arow) * K + kc + akb);
      *(uint4*)&As[arow][akb] = v;
    } else {
      uint4 z = {0,0,0,0}; *(uint4*)&As[arow][akb] = z;
    }
    if (bk < kw){
      uint4 v = *(const uint4*)(Bb + (size_t)(kc + bk) * Nc + n0 + bnb);
      const unsigned short* vs = (const unsigned short*)&v;
      #pragma unroll
      for (int e = 0; e < 8; ++e) Bs[bnb + e][bk] = vs[e];
    } else {
      #pragma unroll
      for (int e = 0; e < 8; ++e) Bs[bnb + e][bk] = 0;
    }
    __syncthreads();
    short8 af = *(const short8*)&As[16 * w + r][q * 8];
    short8 b0 = *(const short8*)&Bs[r][q * 8];
    short8 b1 = *(const short8*)&Bs[16 + r][q * 8];
    short8 b2 = *(const short8*)&Bs[32 + r][q * 8];
    short8 b3 = *(const short8*)&Bs[48 + r][q * 8];
    acc0 = __builtin_amdgcn_mfma_f32_16x16x32_bf16(af, b0, acc0, 0, 0, 0);
    acc1 = __builtin_amdgcn_mfma_f32_16x16x32_bf16(af, b1, acc1, 0, 0, 0);
    acc2 = __builtin_amdgcn_mfma_f32_16x16x32_bf16(af, b2, acc2, 0, 0, 0);
    acc3 = __builtin_amdgcn_mfma_f32_16x16x32_bf16(af, b3, acc3, 0, 0, 0);
    __syncthreads();
  }
  const int row = m0 + 16 * w + q * 4, col0 = n0 + r;
  #pragma unroll
  for (int i = 0; i < 4; ++i){
    size_t base = (size_t)(row + i) * Nc;
    C[base + col0]      = acc0[i];
    C[base + col0 + 16] = acc1[i];
    C[base + col0 + 32] = acc2[i];
    C[base + col0 + 48] = acc3[i];
  }
}

// ---------------- LSTM via MFMA: 16 WGs (2 dirs x 8 h-quarters of 32) ----------------
// Full 64-deep HX rotation: producer block mm writes its h quarter ONCE per step to
// HXd + t*512 + mm*64 (u32); consumers poll the 7 partner producer regions directly
// (one u64 poll per thread, 224 threads). No slot reuse within a launch -> no ABA,
// no reset stores. setup re-poisons all slots to SENT each launch (graph-replay safe).
__global__ __launch_bounds__(256)
void lstm13_kernel(const float* __restrict__ XF, const float* __restrict__ XB,
                   const unsigned int* __restrict__ WT,
                   const float* __restrict__ bih_f, const float* __restrict__ bhh_f,
                   const float* __restrict__ bih_b, const float* __restrict__ bhh_b,
                   unsigned int* __restrict__ HX,
                   float* __restrict__ HT)
{
  __shared__ unsigned int WL[16384];          // Whh slice [128 gate rows][256 K] bf16
  __shared__ unsigned int H16[16 * 132];      // full h [16 M-rows][256 K bf16]
  __shared__ float glds[4][128];

  const int tid = threadIdx.x;
  const int mm = blockIdx.x & 7, dir = blockIdx.x >> 3;
  const int w = tid >> 6, lane = tid & 63, quad = lane >> 4, r = lane & 15;
  const float* Xp = dir ? XB : XF;
  unsigned int* HXd = HX + dir * 32768;

  // nonlinearity thread mapping: tid<128 -> (rowb, j)
  const int rowb = tid >> 5, j = tid & 31;    // rowb in [0,8) but only tid<128 used

  const float* bi = dir ? bih_b : bih_f;
  const float* bh = dir ? bhh_b : bhh_f;
  float bias0 = 0.f, bias1 = 0.f, bias2 = 0.f, bias3 = 0.f;
  if (tid < 128){
    bias0 = bi[0 * 256 + 32 * mm + j] + bh[0 * 256 + 32 * mm + j];
    bias1 = bi[1 * 256 + 32 * mm + j] + bh[1 * 256 + 32 * mm + j];
    bias2 = bi[2 * 256 + 32 * mm + j] + bh[2 * 256 + 32 * mm + j];
    bias3 = bi[3 * 256 + 32 * mm + j] + bh[3 * 256 + 32 * mm + j];
  }

  {
    const uint4* WT4 = (const uint4*)(WT + dir * 131072 + mm * 16384);
    uint4* WL4s = (uint4*)WL;
    #pragma unroll
    for (int s = 0; s < 16; ++s)
      WL4s[s * 256 + tid] = WT4[s * 256 + tid];
  }
  for (int i = tid; i < 16 * 132; i += 256) H16[i] = 0;
  float c = 0.f;
  __syncthreads();

  const uint4* WL4 = (const uint4*)WL;
  const uint4* H16u4 = (const uint4*)H16;

  // consumer poll geometry: tid<224 -> partner pl, u64 slot s (b2 rows, pair pp)
  const int pi = tid >> 5;
  const int pl = pi + (pi >= mm ? 1 : 0);
  const int ps = tid & 31, pb2 = ps >> 4, ppp = ps & 15;

  float4v acc[2];
  auto kchunk = [&](int kc){
    uint4 av = H16u4[(lane & 15) * 33 + kc * 4 + quad];
    short8 af = *(const short8*)&av;
    #pragma unroll
    for (int t = 0; t < 2; ++t){
      int nt = w * 2 + t;
      uint4 bv = WL4[(kc * 8 + nt) * 64 + lane];
      short8 bf = *(const short8*)&bv;
      acc[t] = __builtin_amdgcn_mfma_f32_16x16x32_bf16(af, bf, acc[t], 0, 0, 0);
    }
  };

  for (int t = 0; t < TT; ++t){
    const int tb = dir ? (TT - 1 - t) : t;
    float x0 = 0.f, x1 = 0.f, x2 = 0.f, x3 = 0.f;
    if (tid < 128){
      const float* xr = Xp + (size_t)(tb * 4 + rowb) * 1024 + 32 * mm + j;
      x0 = xr[0]; x1 = xr[256]; x2 = xr[512]; x3 = xr[768];
    }

    acc[0] = (float4v){0,0,0,0}; acc[1] = (float4v){0,0,0,0};
    kchunk(mm);                                  // own K-chunk overlaps the poll
    if (t > 0 && tid < 224){
      const unsigned long long* pg =
        (const unsigned long long*)(HXd + (size_t)(t - 1) * 512 + pl * 64) + ps;
      unsigned long long pv;
      int guard = 0;
      for (;;){
        pv = __hip_atomic_load(pg, __ATOMIC_RELAXED, __HIP_MEMORY_SCOPE_AGENT);
        if (((unsigned int)pv != SENT) && ((unsigned int)(pv >> 32) != SENT)) break;
        if (++guard >= 200000) break;
      }
      H16[pb2 * 132 + 16 * pl + ppp]       = (unsigned int)pv;
      H16[(pb2 + 2) * 132 + 16 * pl + ppp] = (unsigned int)(pv >> 32);
    }
    __syncthreads();
    #pragma unroll
    for (int i = 1; i < 8; ++i)
      kchunk((mm + i) & 7);
    if (quad == 0){
      #pragma unroll
      for (int tt = 0; tt < 2; ++tt){
        int l = (w * 2 + tt) * 16 + r;
        glds[0][l] = acc[tt][0];
        glds[1][l] = acc[tt][1];
        glds[2][l] = acc[tt][2];
        glds[3][l] = acc[tt][3];
      }
    }
    __syncthreads();

    if (tid < 128){
      float gi = glds[rowb][j]      + bias0 + x0;
      float gf = glds[rowb][32 + j] + bias1 + x1;
      float gg = glds[rowb][64 + j] + bias2 + x2;
      float go = glds[rowb][96 + j] + bias3 + x3;
      float si = 1.f / (1.f + __expf(-gi));
      float sf = 1.f / (1.f + __expf(-gf));
      float so = 1.f / (1.f + __expf(-go));
      float tg = 1.f - 2.f / (1.f + __expf(2.f * gg));
      c = sf * c + si * tg;
      float ch = 1.f - 2.f / (1.f + __expf(2.f * c));
      float hval = so * ch;
      if (t == TT - 1){
        HT[(size_t)(dir * 4 + rowb) * RHID + (32 * mm + j)] = hval;
      } else {
        unsigned int own = f2b(hval);
        unsigned int partner = ((unsigned int)__shfl_xor((int)own, 1)) & 0xffffu;
        if ((j & 1) == 0){
          unsigned int v = own | (partner << 16);
          // u32 slot: rows (b2, b2+2) paired into u64s; this thread writes its half
          int u32off = ((rowb & 1) * 16 + (j >> 1)) * 2 + (rowb >> 1);
          H16[rowb * 132 + 16 * mm + (j >> 1)] = v;
          __hip_atomic_store(HXd + (size_t)t * 512 + mm * 64 + u32off, v,
                             __ATOMIC_RELAXED, __HIP_MEMORY_SCOPE_AGENT);
        }
      }
    }
    if (t == TT - 1) break;
    __syncthreads();
  }
}

// ---------------- heads + Poincare projection, fp32 out ----------------
__global__ __launch_bounds__(512)
void head2_kernel(const float* __restrict__ HT,
                  const float* __restrict__ muW, const float* __restrict__ mub,
                  const float* __restrict__ lvW, const float* __restrict__ lvb,
                  float* __restrict__ out)
{
  __shared__ float feat[4][512];
  __shared__ float muv[4][64];
  __shared__ float lvv[4][64];
  int tid = threadIdx.x;
  for (int i = tid; i < 2048; i += 512){
    int rr = i >> 8, k = i & 255;
    int b = rr & 3, d = rr >> 2;
    feat[b][d * 256 + k] = HT[i];
  }
  __syncthreads();
  int w = tid >> 6, lane = tid & 63;
  for (int job = w; job < 512; job += 8){
    int j = job & 63, b = (job >> 6) & 3, mat = job >> 8;
    const float* W = (mat ? lvW : muW) + (size_t)j * 512;
    float s = 0.f;
    #pragma unroll
    for (int e = 0; e < 8; ++e) s += W[lane * 8 + e] * feat[b][lane * 8 + e];
    #pragma unroll
    for (int mm = 32; mm >= 1; mm >>= 1) s += __shfl_xor(s, mm);
    if (lane == 0){
      float v = s + (mat ? lvb[j] : mub[j]);
      if (mat) lvv[b][j] = v; else muv[b][j] = v;
    }
  }
  __syncthreads();
  if (tid < 256){
    int b = tid >> 6, j = tid & 63;
    float mu = muv[b][j];
    float sq = mu * mu;
    #pragma unroll
    for (int mm = 32; mm >= 1; mm >>= 1) sq += __shfl_xor(sq, mm);
    float nrm = sqrtf(sq);
    const float mxn = 1.0f - 4e-3f;
    if (nrm > mxn) mu = mu / nrm * mxn;
    out[b * 64 + j] = mu;
    out[256 + b * 64 + j] = lvv[b][j];
  }
}

extern "C" void kernel_launch(void* const* d_in, const int* in_sizes, int n_in,
                              void* d_out, int out_size, void* d_ws, size_t ws_size,
                              hipStream_t stream)
{
  const int* ei = (const int*)d_in[1];

  float* FW   = (float*)d_ws;
  float* Wbuf = FW + FOFF_WBUF;
  int*   csr_row = (int*)(FW + FOFF_CSR);
  unsigned short* csr_src = (unsigned short*)(FW + FOFF_CSR + 132);
  float* XFp  = FW + FOFF_XFP;
  float* XBp  = FW + FOFF_XBP;
  float* HT   = FW + FOFF_HT;
  unsigned short* XSEQ = (unsigned short*)(FW + FOFF_XSEQ);
  unsigned short* PA   = (unsigned short*)(FW + FOFF_PA);
  unsigned short* PB   = (unsigned short*)(FW + FOFF_PB);
  unsigned short* Pb   = (unsigned short*)(FW + FOFF_P);
  unsigned int*   WT   = (unsigned int*)(FW + FOFF_WE);
  unsigned short* BBF  = (unsigned short*)(FW + FOFF_BBF);
  unsigned int*   HX   = (unsigned int*)(FW + FOFF_SYNC);

  CvtArgs ca;
  static const int wsz[24] = {4096,256,256,256, 65536,256,256,256, 16384,64,64,64,
                              65536,262144,1024,1024, 65536,262144,1024,1024,
                              32768,64,32768,64};
  {
    int acc = 0;
    for (int k = 0; k < 24; ++k){ ca.src[k] = d_in[2 + k]; ca.off[k] = acc; acc += wsz[k]; }
    ca.off[24] = acc;
  }
  int nblk = (SP_TOTAL + 255) / 256 + 1;
  setup_kernel<<<nblk, 256, 0, stream>>>(ca, Wbuf, BBF, Pb, WT, HX,
                                         d_in[0], ei, csr_row, csr_src);

  glayer_kernel<16><<<512, 256, 0, stream>>>(Pb, BBF + BOFF_G0, Wbuf,
                                             WOFF_G0AS, WOFF_G0AD, WOFF_G0B,
                                             csr_row, csr_src, PA);
  glayer_kernel<256><<<512, 256, 0, stream>>>(PA, BBF + BOFF_G1, Wbuf,
                                              WOFF_G1AS, WOFF_G1AD, WOFF_G1B,
                                              csr_row, csr_src, PB);
  glayer2_kernel<<<512, 256, 0, stream>>>(PB, BBF + BOFF_G2, Wbuf,
                                          csr_row, csr_src, XSEQ);

  mmx2_kernel<<<dim3(4, 16, 2), 256, 0, stream>>>(XSEQ, BBF + BOFF_WF, BBF + BOFF_WB,
                                                  XFp, XBp, 256, 1024, 64);

  lstm13_kernel<<<LSTM_GRID, 256, 0, stream>>>(XFp, XBp, WT,
                                               Wbuf + WOFF_BIHF, Wbuf + WOFF_BHHF,
                                               Wbuf + WOFF_BIHB, Wbuf + WOFF_BHHB,
                                               HX, HT);

  head2_kernel<<<1, 512, 0, stream>>>(HT, Wbuf + WOFF_MUW, Wbuf + WOFF_MUB,
                                      Wbuf + WOFF_LVW, Wbuf + WOFF_LVB, (float*)d_out);
}

// Round 9
// 310.131 us; speedup vs baseline: 2.0988x; 1.0227x over previous
//
#include <hip/hip_runtime.h>
#include <hip/hip_bf16.h>

// ---- problem constants ----
#define BSZ 4
#define TT 64
#define NNODE 128
#define NFEAT 16
#define HIDD 64
#define NHEAD 4
#define RHID 256
#define LDIM 64
#define EPG 1024
#define NGRAPH (BSZ*TT)          // 256
#define NTOT (NGRAPH*NNODE)      // 32768
#define ESLOTS (EPG+NNODE)       // 1152

// ---- canonical fp32 weight buffer offsets (floats) ----
#define WOFF_G0W 0
#define WOFF_G0AS 4096
#define WOFF_G0AD 4352
#define WOFF_G0B 4608
#define WOFF_G1W 4864
#define WOFF_G1AS 70400
#define WOFF_G1AD 70656
#define WOFF_G1B 70912
#define WOFF_G2W 71168
#define WOFF_G2AS 87552
#define WOFF_G2AD 87616
#define WOFF_G2B 87680
#define WOFF_WIHF 87744
#define WOFF_WHHF 153280
#define WOFF_BIHF 415424
#define WOFF_BHHF 416448
#define WOFF_WIHB 417472
#define WOFF_WHHB 483008
#define WOFF_BIHB 745152
#define WOFF_BHHB 746176
#define WOFF_MUW 747200
#define WOFF_MUB 779968
#define WOFF_LVW 780032
#define WOFF_LVB 812800
#define WTOTAL   812864

// ---- workspace float offsets ----
#define FOFF_WBUF 4096
#define FOFF_CSR  1052672      // csr_row int[132], csr_src u16[1152]
#define FOFF_SYNC 1314816      // HX: 2 dirs x 64 steps x 8 producers x 64 u32 (full rotation, no reset)
#define FOFF_WE   1576960      // WTB (bf16 B-frag Whh, 262144 uints)
#define FOFF_BBF  1900000      // bf16 B matrices (u16 view)
#define FOFF_XFP  2756608
#define FOFF_XBP  3018752
#define FOFF_HT   3280896
#define FOFF_XSEQ 3282944
#define FOFF_PA   3291136      // P0 [32768][256] bf16
#define FOFF_PB   5388288      // P1 [32768][256] bf16
#define FOFF_P    7485440      // X  [32768][16]  bf16

// bf16 B-matrix u16 offsets inside BBF (G0/G1/G2 stored TRANSPOSED [out][in])
#define BOFF_G0 0
#define BOFF_G1 4096
#define BOFF_G2 69632
#define BOFF_WF 86016
#define BOFF_WB 151552
#define BTOTAL  217088

#define LSTM_GRID 16           // 2 dirs x 8 h-quarters (32 h each)
#define HX_WORDS  65536        // 2 x 64 x 512 u32

// setup phases
#define SP_CVTX  (WTOTAL + BTOTAL)            // 1029952
#define SP_WHH   (SP_CVTX + NTOT*NFEAT)       // 1554240
#define SP_HX    (SP_WHH + 262144)            // 1816384
#define SP_TOTAL (SP_HX + HX_WORDS)           // 1881920

#define SENT 0xFFFFFFFFu

typedef __attribute__((ext_vector_type(8))) short short8;
typedef __attribute__((ext_vector_type(4))) float float4v;

__device__ __forceinline__ float b2f(unsigned short u){
  union { unsigned int i; float f; } v; v.i = ((unsigned int)u) << 16; return v.f;
}
__device__ __forceinline__ unsigned short f2b(float f){
  __hip_bfloat16 h = __float2bfloat16(f);
  union { __hip_bfloat16 h; unsigned short u; } v; v.h = h; return v.u;
}
__device__ __forceinline__ float ldf(const void* p, int i, int flag){
  return flag ? b2f(((const unsigned short*)p)[i]) : ((const float*)p)[i];
}
__device__ __forceinline__ float h2f(unsigned short s){
  union { _Float16 hh; unsigned short s; } u; u.s = s; return (float)u.hh;
}
__device__ __forceinline__ unsigned short f2h(float f){
  union { _Float16 hh; unsigned short s; } u; u.hh = (_Float16)f; return u.s;
}
__device__ __forceinline__ int sniff32(const unsigned short* w){
  int ok = 0;
  #pragma unroll
  for (int i = 0; i < 32; ++i){
    float a = fabsf(b2f(w[2 * i]));
    if (a > 1e-8f && a < 4.f) ok++;
  }
  return ok >= 16 ? 1 : 0;
}

// ---------------- fused setup: sniff(once/block) + cvtw + packb(T) + cvtx + packwhh + HX + CSR ----------------
struct CvtArgs {
  const void* src[24];
  int off[25];
};
__global__ void setup_kernel(CvtArgs a,
                             float* __restrict__ W, unsigned short* __restrict__ BBF,
                             unsigned short* __restrict__ P, unsigned int* __restrict__ WT,
                             unsigned int* __restrict__ HX,
                             const void* __restrict__ x, const int* __restrict__ ei,
                             int* __restrict__ csr_row, unsigned short* __restrict__ csr_src)
{
  __shared__ int cnt[NNODE];
  __shared__ int off[NNODE];
  __shared__ int wo[NNODE];
  __shared__ int sfl;
  const int tid = threadIdx.x;

  if (blockIdx.x == gridDim.x - 1){
    if (tid < NNODE) cnt[tid] = 0;
    __syncthreads();
    for (int i = tid; i < ESLOTS; i += 256){
      int d = (i < EPG) ? ei[EPG + i] : (i - EPG);
      atomicAdd(&cnt[d], 1);
    }
    __syncthreads();
    if (tid < NNODE) off[tid] = cnt[tid];
    for (int o = 1; o < NNODE; o <<= 1){
      __syncthreads();
      int t = (tid < NNODE && tid >= o) ? off[tid - o] : 0;
      __syncthreads();
      if (tid < NNODE) off[tid] += t;
    }
    __syncthreads();
    if (tid < NNODE){
      wo[tid] = off[tid] - cnt[tid];
      csr_row[tid + 1] = off[tid];
    }
    if (tid == 0) csr_row[0] = 0;
    __syncthreads();
    for (int i = tid; i < ESLOTS; i += 256){
      int s, d;
      if (i < EPG){ s = ei[i]; d = ei[EPG + i]; } else { s = i - EPG; d = i - EPG; }
      int pos = atomicAdd(&wo[d], 1);
      csr_src[pos] = (unsigned short)s;
    }
    return;
  }

  // sniff ONCE per block (was per-thread: 1.8M x 32 redundant loads)
  if (tid == 0) sfl = sniff32((const unsigned short*)a.src[0]);
  __syncthreads();
  int id = blockIdx.x * blockDim.x + tid;
  if (id >= SP_TOTAL) return;
  const int fl = sfl;

  if (id < WTOTAL){
    int k = 0;
    while (id >= a.off[k + 1]) ++k;
    W[id] = ldf(a.src[k], id - a.off[k], fl);
  } else if (id < WTOTAL + BTOTAL){
    int r = id - WTOTAL;
    float v;
    if (r < BOFF_G1){
      int o = r >> 4, k = r & 15;
      v = ldf(a.src[0], k * 256 + o, fl);
    } else if (r < BOFF_G2){
      int rr = r - BOFF_G1; int o = rr >> 8, k = rr & 255;
      v = ldf(a.src[4], k * 256 + o, fl);
    } else if (r < BOFF_WF){
      int rr = r - BOFF_G2; int o = rr >> 8, k = rr & 255;
      v = ldf(a.src[8], k * 64 + o, fl);
    } else if (r < BOFF_WB){
      int q = r - BOFF_WF; int k = q >> 10, n = q & 1023;
      v = ldf(a.src[12], n * 64 + k, fl);
    } else {
      int q = r - BOFF_WB; int k = q >> 10, n = q & 1023;
      v = ldf(a.src[16], n * 64 + k, fl);
    }
    BBF[r] = f2b(v);
  } else if (id < SP_CVTX + NTOT * NFEAT){
    int r = id - SP_CVTX;
    P[r] = fl ? ((const unsigned short*)x)[r] : f2b(((const float*)x)[r]);
  } else if (id < SP_HX){
    // Whh B-fragment pack for 8-way split: block mm owns gate rows g*256 + 32*mm + [0,32)
    int r0 = id - SP_WHH;
    int c = r0 & 3;
    int lane = (r0 >> 2) & 63;
    int nt = (r0 >> 8) & 7;
    int kc = (r0 >> 11) & 7;
    int mm = (r0 >> 14) & 7;
    int dir = r0 >> 17;
    int l = nt * 16 + (lane & 15);             // [0,128)
    int u = (l >> 5) * 256 + 32 * mm + (l & 31);
    int k0 = kc * 32 + ((lane >> 4) << 3) + 2 * c;
    const void* Wsrc = dir ? a.src[17] : a.src[13];
    unsigned short va = f2b(ldf(Wsrc, u * RHID + k0, fl));
    unsigned short vb = f2b(ldf(Wsrc, u * RHID + k0 + 1, fl));
    WT[r0] = (unsigned int)va | ((unsigned int)vb << 16);
  } else {
    HX[id - SP_HX] = SENT;
  }
}

// ---------------- GAT 4-head half-layer kernel (L0/L1): 512 blocks, MFMA agg ----------------
// r8: shuffle-free logits; B prefetch. r9: A-operand prefetch (1 K-iter ahead) +
// per-(n,hl) softmax max/den precompute with all 256 threads (single-pass scatter).
template<int KV>
__global__ __launch_bounds__(256)
void glayer_kernel(const unsigned short* __restrict__ Pin,
                   const unsigned short* __restrict__ BT,
                   const float* __restrict__ Wbuf,
                   int asoff, int adoff, int boff,
                   const int* __restrict__ csr_row, const unsigned short* __restrict__ csr_src,
                   unsigned short* __restrict__ Pout)
{
  __shared__ unsigned short HT_[128 * 136];   // h^T [col][node]
  __shared__ unsigned short AD[128 * 136];    // union: Bst / dense-alpha [dst][src]
  __shared__ unsigned short ALS16[256];
  __shared__ unsigned short ALD16[256];
  __shared__ float MXf[256];
  __shared__ float IDf[256];
  __shared__ float ASL[128];
  __shared__ float ADL[128];
  __shared__ int   rowL[132];
  __shared__ unsigned char srcL[1152];

  const int tid = threadIdx.x;
  const int g = blockIdx.x >> 1, hb = blockIdx.x & 1;
  const int c0 = hb * 128;
  const int w = tid >> 6, lane = tid & 63, q = lane >> 4, r = lane & 15;
  unsigned short* Bst = AD;

  for (int i = tid; i < 129; i += 256) rowL[i] = csr_row[i];
  for (int i = tid; i < 1152; i += 256) srcL[i] = (unsigned char)csr_src[i];
  if (tid < 128){
    ASL[tid] = Wbuf[asoff + c0 + tid];
    ADL[tid] = Wbuf[adoff + c0 + tid];
  }
  __syncthreads();

  // ---- GEMM producing h^T (A and B both prefetched one iter ahead) ----
  {
    float4v acc0[8], acc1[8];
    #pragma unroll
    for (int i = 0; i < 8; ++i){ acc0[i] = (float4v){0,0,0,0}; acc1[i] = (float4v){0,0,0,0}; }
    const int KR = (KV + 31) / 32;
    const int bn = tid >> 1, bkb = (tid & 1) * 16;
    uint4 z = {0,0,0,0};
    uint4 vb0 = z, vb1 = z;
    if (bkb < KV)     vb0 = *(const uint4*)(BT + (size_t)(c0 + bn) * KV + bkb);
    if (bkb + 8 < KV) vb1 = *(const uint4*)(BT + (size_t)(c0 + bn) * KV + bkb + 8);
    const short8 za = {0,0,0,0,0,0,0,0};
    short8 a0c = za, a1c = za;
    if (KV >= 32 || q < 2){
      a0c = *(const short8*)(Pin + (size_t)(g * 128 + 16 * w       + r) * KV + q * 8);
      a1c = *(const short8*)(Pin + (size_t)(g * 128 + 16 * (w + 4) + r) * KV + q * 8);
    }
    for (int kr = 0; kr < KR; ++kr){
      const int kc = kr * 32;
      __syncthreads();
      *(uint4*)&Bst[bn * 40 + bkb] = vb0;
      *(uint4*)&Bst[bn * 40 + bkb + 8] = vb1;
      __syncthreads();
      short8 a0n = za, a1n = za;
      if (kr + 1 < KR){
        const int kc2 = kc + 32;
        vb0 = *(const uint4*)(BT + (size_t)(c0 + bn) * KV + kc2 + bkb);
        vb1 = *(const uint4*)(BT + (size_t)(c0 + bn) * KV + kc2 + bkb + 8);
        a0n = *(const short8*)(Pin + (size_t)(g * 128 + 16 * w       + r) * KV + kc2 + q * 8);
        a1n = *(const short8*)(Pin + (size_t)(g * 128 + 16 * (w + 4) + r) * KV + kc2 + q * 8);
      }
      #pragma unroll
      for (int nt = 0; nt < 8; ++nt){
        short8 bf = *(const short8*)&Bst[(16 * nt + r) * 40 + q * 8];
        acc0[nt] = __builtin_amdgcn_mfma_f32_16x16x32_bf16(a0c, bf, acc0[nt], 0, 0, 0);
        acc1[nt] = __builtin_amdgcn_mfma_f32_16x16x32_bf16(a1c, bf, acc1[nt], 0, 0, 0);
      }
      a0c = a0n; a1c = a1n;
    }
    __syncthreads();
    #pragma unroll
    for (int nt = 0; nt < 8; ++nt)
      #pragma unroll
      for (int i = 0; i < 4; ++i){
        HT_[(16 * nt + r) * 136 + 16 * w       + q * 4 + i] = f2b(acc0[nt][i]);
        HT_[(16 * nt + r) * 136 + 16 * (w + 4) + q * 4 + i] = f2b(acc1[nt][i]);
      }
    __syncthreads();
  }

  // ---- attention logits: thread (n, hl) dots h^T column n over its head's 64 cols ----
  {
    const int n = tid & 127, hl = tid >> 7;
    const int cb = hl * 64;
    float vs = 0.f, vd = 0.f;
    #pragma unroll 8
    for (int c = 0; c < 64; ++c){
      float e = b2f(HT_[(cb + c) * 136 + n]);
      vs += e * ASL[cb + c];
      vd += e * ADL[cb + c];
    }
    ALS16[n * 2 + hl] = f2h(vs);
    ALD16[n * 2 + hl] = f2h(vd);
  }
  __syncthreads();

  // ---- softmax max/den precompute: both heads in parallel (256 threads) ----
  {
    const int n = tid & 127, hl = tid >> 7;
    float aldv = h2f(ALD16[n * 2 + hl]);
    int rs = rowL[n], re = rowL[n + 1];
    float mx = -3e38f, den = 0.f;
    for (int j = rs; j < re; ++j){
      float v = h2f(ALS16[srcL[j] * 2 + hl]) + aldv;
      v = v > 0.f ? v : 0.2f * v;
      if (v > mx){ den = den * __expf(mx - v) + 1.f; mx = v; }
      else den += __expf(v - mx);
    }
    MXf[n * 2 + hl] = mx;
    IDf[n * 2 + hl] = 1.f / (den + 1e-16f);
  }
  __syncthreads();

  // ---- per-head: dense scatter (single pass) + MFMA agg + plain-store epilogue ----
  for (int hl = 0; hl < 2; ++hl){
    for (int i = tid; i < 8704; i += 256) ((unsigned int*)AD)[i] = 0;
    __syncthreads();
    if (tid < 128){
      int n = tid;
      float aldv = h2f(ALD16[n * 2 + hl]);
      float mx = MXf[n * 2 + hl], iden = IDf[n * 2 + hl];
      int rs = rowL[n], re = rowL[n + 1];
      for (int j = rs; j < re; ++j){
        float v = h2f(ALS16[srcL[j] * 2 + hl]) + aldv;
        v = v > 0.f ? v : 0.2f * v;
        float al = __expf(v - mx) * iden;
        int s = srcL[j];
        AD[n * 136 + s] = f2b(b2f(AD[n * 136 + s]) + al);
      }
    }
    __syncthreads();
    float4v am[2][4];
    #pragma unroll
    for (int mt = 0; mt < 2; ++mt)
      #pragma unroll
      for (int nt = 0; nt < 4; ++nt) am[mt][nt] = (float4v){0,0,0,0};
    #pragma unroll
    for (int kc = 0; kc < 4; ++kc){
      short8 af0 = *(const short8*)&AD[(w * 32      + r) * 136 + kc * 32 + q * 8];
      short8 af1 = *(const short8*)&AD[(w * 32 + 16 + r) * 136 + kc * 32 + q * 8];
      #pragma unroll
      for (int nt = 0; nt < 4; ++nt){
        short8 bf = *(const short8*)&HT_[(hl * 64 + nt * 16 + r) * 136 + kc * 32 + q * 8];
        am[0][nt] = __builtin_amdgcn_mfma_f32_16x16x32_bf16(af0, bf, am[0][nt], 0, 0, 0);
        am[1][nt] = __builtin_amdgcn_mfma_f32_16x16x32_bf16(af1, bf, am[1][nt], 0, 0, 0);
      }
    }
    #pragma unroll
    for (int mt = 0; mt < 2; ++mt)
      #pragma unroll
      for (int nt = 0; nt < 4; ++nt){
        int col = hl * 64 + nt * 16 + r;
        float bz = Wbuf[boff + c0 + col];
        #pragma unroll
        for (int i = 0; i < 4; ++i){
          int dst = w * 32 + mt * 16 + q * 4 + i;
          float v = am[mt][nt][i] + bz;
          v = v > 0.f ? v : 0.f;
          Pout[(size_t)(g * 128 + dst) * 256 + c0 + col] = f2b(v);
        }
      }
    __syncthreads();
  }
}

// ---------------- GAT layer 2 (1 head) + pool: 512 blocks ----------------
__global__ __launch_bounds__(256)
void glayer2_kernel(const unsigned short* __restrict__ Pin,
                    const unsigned short* __restrict__ BT,
                    const float* __restrict__ Wbuf,
                    const int* __restrict__ csr_row, const unsigned short* __restrict__ csr_src,
                    unsigned short* __restrict__ XSEQ)
{
  __shared__ unsigned short HT_[64 * 136];
  __shared__ unsigned short AD[128 * 136];
  __shared__ float ALSf[128];
  __shared__ float ALDf[128];
  __shared__ float ASL2[64];
  __shared__ float ADL2[64];
  __shared__ int   rowL[132];
  __shared__ unsigned char srcL[1152];
  __shared__ float pools[4][64];

  const int tid = threadIdx.x;
  const int g = blockIdx.x >> 1, hb = blockIdx.x & 1;
  const int w = tid >> 6, lane = tid & 63, q = lane >> 4, r = lane & 15;
  unsigned short* Bst = AD;

  for (int i = tid; i < 129; i += 256) rowL[i] = csr_row[i];
  for (int i = tid; i < 1152; i += 256) srcL[i] = (unsigned char)csr_src[i];
  if (tid < 64){
    ASL2[tid] = Wbuf[WOFF_G2AS + tid];
    ADL2[tid] = Wbuf[WOFF_G2AD + tid];
  }
  __syncthreads();

  // ---- GEMM h2^T [64 cols][128 nodes] (A and B prefetched one iter ahead) ----
  {
    float4v acc0[4], acc1[4];
    #pragma unroll
    for (int i = 0; i < 4; ++i){ acc0[i] = (float4v){0,0,0,0}; acc1[i] = (float4v){0,0,0,0}; }
    const int bn = tid >> 2, bkb = (tid & 3) * 8;
    const short8 za = {0,0,0,0,0,0,0,0};
    uint4 vb = *(const uint4*)(BT + (size_t)bn * 256 + bkb);
    short8 a0c = *(const short8*)(Pin + (size_t)(g * 128 + 16 * w       + r) * 256 + q * 8);
    short8 a1c = *(const short8*)(Pin + (size_t)(g * 128 + 16 * (w + 4) + r) * 256 + q * 8);
    for (int kr = 0; kr < 8; ++kr){
      const int kc = kr * 32;
      __syncthreads();
      *(uint4*)&Bst[bn * 40 + bkb] = vb;
      __syncthreads();
      short8 a0n = za, a1n = za;
      if (kr < 7){
        vb = *(const uint4*)(BT + (size_t)bn * 256 + kc + 32 + bkb);
        a0n = *(const short8*)(Pin + (size_t)(g * 128 + 16 * w       + r) * 256 + kc + 32 + q * 8);
        a1n = *(const short8*)(Pin + (size_t)(g * 128 + 16 * (w + 4) + r) * 256 + kc + 32 + q * 8);
      }
      #pragma unroll
      for (int nt = 0; nt < 4; ++nt){
        short8 bf = *(const short8*)&Bst[(16 * nt + r) * 40 + q * 8];
        acc0[nt] = __builtin_amdgcn_mfma_f32_16x16x32_bf16(a0c, bf, acc0[nt], 0, 0, 0);
        acc1[nt] = __builtin_amdgcn_mfma_f32_16x16x32_bf16(a1c, bf, acc1[nt], 0, 0, 0);
      }
      a0c = a0n; a1c = a1n;
    }
    __syncthreads();
    #pragma unroll
    for (int nt = 0; nt < 4; ++nt)
      #pragma unroll
      for (int i = 0; i < 4; ++i){
        HT_[(16 * nt + r) * 136 + 16 * w       + q * 4 + i] = f2b(acc0[nt][i]);
        HT_[(16 * nt + r) * 136 + 16 * (w + 4) + q * 4 + i] = f2b(acc1[nt][i]);
      }
    __syncthreads();
  }

  // ---- attention logits: thread n dots h2^T column n over 64 cols ----
  if (tid < 128){
    const int n = tid;
    float vs = 0.f, vd = 0.f;
    #pragma unroll 8
    for (int c = 0; c < 64; ++c){
      float e = b2f(HT_[c * 136 + n]);
      vs += e * ASL2[c];
      vd += e * ADL2[c];
    }
    ALSf[n] = vs;
    ALDf[n] = vd;
  }
  __syncthreads();
  for (int i = tid; i < 8704; i += 256) ((unsigned int*)AD)[i] = 0;
  __syncthreads();
  if (tid < 128){
    int n = tid;
    float aldv = ALDf[n];
    int rs = rowL[n], re = rowL[n + 1];
    float mx = -3e38f, den = 0.f;
    for (int j = rs; j < re; ++j){
      float v = ALSf[srcL[j]] + aldv;
      v = v > 0.f ? v : 0.2f * v;
      if (v > mx){ den = den * __expf(mx - v) + 1.f; mx = v; }
      else den += __expf(v - mx);
    }
    float iden = 1.f / (den + 1e-16f);
    for (int j = rs; j < re; ++j){
      float v = ALSf[srcL[j]] + aldv;
      v = v > 0.f ? v : 0.2f * v;
      float al = __expf(v - mx) * iden;
      int s = srcL[j];
      AD[n * 136 + s] = f2b(b2f(AD[n * 136 + s]) + al);
    }
  }
  __syncthreads();
  float4v am[2][4];
  #pragma unroll
  for (int mt = 0; mt < 2; ++mt)
    #pragma unroll
    for (int nt = 0; nt < 4; ++nt) am[mt][nt] = (float4v){0,0,0,0};
  #pragma unroll
  for (int kc = 0; kc < 4; ++kc){
    short8 af0 = *(const short8*)&AD[(w * 32      + r) * 136 + kc * 32 + q * 8];
    short8 af1 = *(const short8*)&AD[(w * 32 + 16 + r) * 136 + kc * 32 + q * 8];
    #pragma unroll
    for (int nt = 0; nt < 4; ++nt){
      short8 bf = *(const short8*)&HT_[(nt * 16 + r) * 136 + kc * 32 + q * 8];
      am[0][nt] = __builtin_amdgcn_mfma_f32_16x16x32_bf16(af0, bf, am[0][nt], 0, 0, 0);
      am[1][nt] = __builtin_amdgcn_mfma_f32_16x16x32_bf16(af1, bf, am[1][nt], 0, 0, 0);
    }
  }
  float psum[4] = {0.f, 0.f, 0.f, 0.f};
  #pragma unroll
  for (int nt = 0; nt < 4; ++nt){
    int col = nt * 16 + r;
    float bz = Wbuf[WOFF_G2B + col];
    #pragma unroll
    for (int mt = 0; mt < 2; ++mt)
      #pragma unroll
      for (int i = 0; i < 4; ++i){
        float v = am[mt][nt][i] + bz;
        psum[nt] += (v > 0.f ? v : 0.f);
      }
    psum[nt] += __shfl_xor(psum[nt], 16);
    psum[nt] += __shfl_xor(psum[nt], 32);
  }
  if (q == 0){
    #pragma unroll
    for (int nt = 0; nt < 4; ++nt) pools[w][nt * 16 + r] = psum[nt];
  }
  __syncthreads();
  if (tid < 64 && (tid >> 5) == hb){
    float s = pools[0][tid] + pools[1][tid] + pools[2][tid] + pools[3][tid];
    int b = g >> 6, tq = g & 63;
    XSEQ[(size_t)(tq * BSZ + b) * HIDD + tid] = f2b(s);
  }
}

// ---------------- MFMA matmul for BOTH Wih GEMMs in one launch (z = dir) ----------------
__global__ __launch_bounds__(256)
void mmx2_kernel(const unsigned short* __restrict__ A,
                 const unsigned short* __restrict__ B0, const unsigned short* __restrict__ B1,
                 float* __restrict__ C0, float* __restrict__ C1, int M, int Nc, int K)
{
  __shared__ unsigned short As[64][40];
  __shared__ unsigned short Bs[64][40];
  const unsigned short* Bb = blockIdx.z ? B1 : B0;
  float* C = blockIdx.z ? C1 : C0;
  const int tid = threadIdx.x;
  const int w = tid >> 6, lane = tid & 63, q = lane >> 4, r = lane & 15;
  const int m0 = blockIdx.x * 64, n0 = blockIdx.y * 64;
  float4v acc0 = {0,0,0,0}, acc1 = {0,0,0,0}, acc2 = {0,0,0,0}, acc3 = {0,0,0,0};
  const int arow = tid >> 2, akb = (tid & 3) * 8;
  const int bk = tid >> 3, bnb = (tid & 7) * 8;
  for (int kc = 0; kc < K; kc += 32){
    int kw = K - kc; if (kw > 32) kw = 32;
    if (akb < kw){
      uint4 v = *(const uint4*)(A + (size_t)(m0 + arow) * K + kc + akb);
      *(uint4*)&As[arow][akb] = v;
    } else {
      uint4 z = {0,0,0,0}; *(uint4*)&As[arow][akb] = z;
    }
    if (bk < kw){
      uint4 v = *(const uint4*)(Bb + (size_t)(kc + bk) * Nc + n0 + bnb);
      const unsigned short* vs = (const unsigned short*)&v;
      #pragma unroll
      for (int e = 0; e < 8; ++e) Bs[bnb + e][bk] = vs[e];
    } else {
      #pragma unroll
      for (int e = 0; e < 8; ++e) Bs[bnb + e][bk] = 0;
    }
    __syncthreads();
    short8 af = *(const short8*)&As[16 * w + r][q * 8];
    short8 b0 = *(const short8*)&Bs[r][q * 8];
    short8 b1 = *(const short8*)&Bs[16 + r][q * 8];
    short8 b2 = *(const short8*)&Bs[32 + r][q * 8];
    short8 b3 = *(const short8*)&Bs[48 + r][q * 8];
    acc0 = __builtin_amdgcn_mfma_f32_16x16x32_bf16(af, b0, acc0, 0, 0, 0);
    acc1 = __builtin_amdgcn_mfma_f32_16x16x32_bf16(af, b1, acc1, 0, 0, 0);
    acc2 = __builtin_amdgcn_mfma_f32_16x16x32_bf16(af, b2, acc2, 0, 0, 0);
    acc3 = __builtin_amdgcn_mfma_f32_16x16x32_bf16(af, b3, acc3, 0, 0, 0);
    __syncthreads();
  }
  const int row = m0 + 16 * w + q * 4, col0 = n0 + r;
  #pragma unroll
  for (int i = 0; i < 4; ++i){
    size_t base = (size_t)(row + i) * Nc;
    C[base + col0]      = acc0[i];
    C[base + col0 + 16] = acc1[i];
    C[base + col0 + 32] = acc2[i];
    C[base + col0 + 48] = acc3[i];
  }
}

// ---------------- LSTM via MFMA: 16 WGs (2 dirs x 8 h-quarters of 32) ----------------
// Full 64-deep HX rotation: producer block mm writes its h quarter ONCE per step to
// HXd + t*512 + mm*64 (u32); consumers poll the 7 partner producer regions directly
// (one u64 poll per thread, 224 threads). No slot reuse within a launch -> no ABA,
// no reset stores. setup re-poisons all slots to SENT each launch (graph-replay safe).
__global__ __launch_bounds__(256)
void lstm13_kernel(const float* __restrict__ XF, const float* __restrict__ XB,
                   const unsigned int* __restrict__ WT,
                   const float* __restrict__ bih_f, const float* __restrict__ bhh_f,
                   const float* __restrict__ bih_b, const float* __restrict__ bhh_b,
                   unsigned int* __restrict__ HX,
                   float* __restrict__ HT)
{
  __shared__ unsigned int WL[16384];          // Whh slice [128 gate rows][256 K] bf16
  __shared__ unsigned int H16[16 * 132];      // full h [16 M-rows][256 K bf16]
  __shared__ float glds[4][128];

  const int tid = threadIdx.x;
  const int mm = blockIdx.x & 7, dir = blockIdx.x >> 3;
  const int w = tid >> 6, lane = tid & 63, quad = lane >> 4, r = lane & 15;
  const float* Xp = dir ? XB : XF;
  unsigned int* HXd = HX + dir * 32768;

  // nonlinearity thread mapping: tid<128 -> (rowb, j)
  const int rowb = tid >> 5, j = tid & 31;    // rowb in [0,8) but only tid<128 used

  const float* bi = dir ? bih_b : bih_f;
  const float* bh = dir ? bhh_b : bhh_f;
  float bias0 = 0.f, bias1 = 0.f, bias2 = 0.f, bias3 = 0.f;
  if (tid < 128){
    bias0 = bi[0 * 256 + 32 * mm + j] + bh[0 * 256 + 32 * mm + j];
    bias1 = bi[1 * 256 + 32 * mm + j] + bh[1 * 256 + 32 * mm + j];
    bias2 = bi[2 * 256 + 32 * mm + j] + bh[2 * 256 + 32 * mm + j];
    bias3 = bi[3 * 256 + 32 * mm + j] + bh[3 * 256 + 32 * mm + j];
  }

  {
    const uint4* WT4 = (const uint4*)(WT + dir * 131072 + mm * 16384);
    uint4* WL4s = (uint4*)WL;
    #pragma unroll
    for (int s = 0; s < 16; ++s)
      WL4s[s * 256 + tid] = WT4[s * 256 + tid];
  }
  for (int i = tid; i < 16 * 132; i += 256) H16[i] = 0;
  float c = 0.f;
  __syncthreads();

  const uint4* WL4 = (const uint4*)WL;
  const uint4* H16u4 = (const uint4*)H16;

  // consumer poll geometry: tid<224 -> partner pl, u64 slot s (b2 rows, pair pp)
  const int pi = tid >> 5;
  const int pl = pi + (pi >= mm ? 1 : 0);
  const int ps = tid & 31, pb2 = ps >> 4, ppp = ps & 15;

  float4v acc[2];
  auto kchunk = [&](int kc){
    uint4 av = H16u4[(lane & 15) * 33 + kc * 4 + quad];
    short8 af = *(const short8*)&av;
    #pragma unroll
    for (int t = 0; t < 2; ++t){
      int nt = w * 2 + t;
      uint4 bv = WL4[(kc * 8 + nt) * 64 + lane];
      short8 bf = *(const short8*)&bv;
      acc[t] = __builtin_amdgcn_mfma_f32_16x16x32_bf16(af, bf, acc[t], 0, 0, 0);
    }
  };

  for (int t = 0; t < TT; ++t){
    const int tb = dir ? (TT - 1 - t) : t;
    float x0 = 0.f, x1 = 0.f, x2 = 0.f, x3 = 0.f;
    if (tid < 128){
      const float* xr = Xp + (size_t)(tb * 4 + rowb) * 1024 + 32 * mm + j;
      x0 = xr[0]; x1 = xr[256]; x2 = xr[512]; x3 = xr[768];
    }

    acc[0] = (float4v){0,0,0,0}; acc[1] = (float4v){0,0,0,0};
    kchunk(mm);                                  // own K-chunk overlaps the poll
    if (t > 0 && tid < 224){
      const unsigned long long* pg =
        (const unsigned long long*)(HXd + (size_t)(t - 1) * 512 + pl * 64) + ps;
      unsigned long long pv;
      int guard = 0;
      for (;;){
        pv = __hip_atomic_load(pg, __ATOMIC_RELAXED, __HIP_MEMORY_SCOPE_AGENT);
        if (((unsigned int)pv != SENT) && ((unsigned int)(pv >> 32) != SENT)) break;
        if (++guard >= 200000) break;
      }
      H16[pb2 * 132 + 16 * pl + ppp]       = (unsigned int)pv;
      H16[(pb2 + 2) * 132 + 16 * pl + ppp] = (unsigned int)(pv >> 32);
    }
    __syncthreads();
    #pragma unroll
    for (int i = 1; i < 8; ++i)
      kchunk((mm + i) & 7);
    if (quad == 0){
      #pragma unroll
      for (int tt = 0; tt < 2; ++tt){
        int l = (w * 2 + tt) * 16 + r;
        glds[0][l] = acc[tt][0];
        glds[1][l] = acc[tt][1];
        glds[2][l] = acc[tt][2];
        glds[3][l] = acc[tt][3];
      }
    }
    __syncthreads();

    if (tid < 128){
      float gi = glds[rowb][j]      + bias0 + x0;
      float gf = glds[rowb][32 + j] + bias1 + x1;
      float gg = glds[rowb][64 + j] + bias2 + x2;
      float go = glds[rowb][96 + j] + bias3 + x3;
      float si = 1.f / (1.f + __expf(-gi));
      float sf = 1.f / (1.f + __expf(-gf));
      float so = 1.f / (1.f + __expf(-go));
      float tg = 1.f - 2.f / (1.f + __expf(2.f * gg));
      c = sf * c + si * tg;
      float ch = 1.f - 2.f / (1.f + __expf(2.f * c));
      float hval = so * ch;
      if (t == TT - 1){
        HT[(size_t)(dir * 4 + rowb) * RHID + (32 * mm + j)] = hval;
      } else {
        unsigned int own = f2b(hval);
        unsigned int partner = ((unsigned int)__shfl_xor((int)own, 1)) & 0xffffu;
        if ((j & 1) == 0){
          unsigned int v = own | (partner << 16);
          // u32 slot: rows (b2, b2+2) paired into u64s; this thread writes its half
          int u32off = ((rowb & 1) * 16 + (j >> 1)) * 2 + (rowb >> 1);
          H16[rowb * 132 + 16 * mm + (j >> 1)] = v;
          __hip_atomic_store(HXd + (size_t)t * 512 + mm * 64 + u32off, v,
                             __ATOMIC_RELAXED, __HIP_MEMORY_SCOPE_AGENT);
        }
      }
    }
    if (t == TT - 1) break;
    __syncthreads();
  }
}

// ---------------- heads + Poincare projection, fp32 out ----------------
__global__ __launch_bounds__(512)
void head2_kernel(const float* __restrict__ HT,
                  const float* __restrict__ muW, const float* __restrict__ mub,
                  const float* __restrict__ lvW, const float* __restrict__ lvb,
                  float* __restrict__ out)
{
  __shared__ float feat[4][512];
  __shared__ float muv[4][64];
  __shared__ float lvv[4][64];
  int tid = threadIdx.x;
  for (int i = tid; i < 2048; i += 512){
    int rr = i >> 8, k = i & 255;
    int b = rr & 3, d = rr >> 2;
    feat[b][d * 256 + k] = HT[i];
  }
  __syncthreads();
  int w = tid >> 6, lane = tid & 63;
  for (int job = w; job < 512; job += 8){
    int j = job & 63, b = (job >> 6) & 3, mat = job >> 8;
    const float* W = (mat ? lvW : muW) + (size_t)j * 512;
    float s = 0.f;
    #pragma unroll
    for (int e = 0; e < 8; ++e) s += W[lane * 8 + e] * feat[b][lane * 8 + e];
    #pragma unroll
    for (int mm = 32; mm >= 1; mm >>= 1) s += __shfl_xor(s, mm);
    if (lane == 0){
      float v = s + (mat ? lvb[j] : mub[j]);
      if (mat) lvv[b][j] = v; else muv[b][j] = v;
    }
  }
  __syncthreads();
  if (tid < 256){
    int b = tid >> 6, j = tid & 63;
    float mu = muv[b][j];
    float sq = mu * mu;
    #pragma unroll
    for (int mm = 32; mm >= 1; mm >>= 1) sq += __shfl_xor(sq, mm);
    float nrm = sqrtf(sq);
    const float mxn = 1.0f - 4e-3f;
    if (nrm > mxn) mu = mu / nrm * mxn;
    out[b * 64 + j] = mu;
    out[256 + b * 64 + j] = lvv[b][j];
  }
}

extern "C" void kernel_launch(void* const* d_in, const int* in_sizes, int n_in,
                              void* d_out, int out_size, void* d_ws, size_t ws_size,
                              hipStream_t stream)
{
  const int* ei = (const int*)d_in[1];

  float* FW   = (float*)d_ws;
  float* Wbuf = FW + FOFF_WBUF;
  int*   csr_row = (int*)(FW + FOFF_CSR);
  unsigned short* csr_src = (unsigned short*)(FW + FOFF_CSR + 132);
  float* XFp  = FW + FOFF_XFP;
  float* XBp  = FW + FOFF_XBP;
  float* HT   = FW + FOFF_HT;
  unsigned short* XSEQ = (unsigned short*)(FW + FOFF_XSEQ);
  unsigned short* PA   = (unsigned short*)(FW + FOFF_PA);
  unsigned short* PB   = (unsigned short*)(FW + FOFF_PB);
  unsigned short* Pb   = (unsigned short*)(FW + FOFF_P);
  unsigned int*   WT   = (unsigned int*)(FW + FOFF_WE);
  unsigned short* BBF  = (unsigned short*)(FW + FOFF_BBF);
  unsigned int*   HX   = (unsigned int*)(FW + FOFF_SYNC);

  CvtArgs ca;
  static const int wsz[24] = {4096,256,256,256, 65536,256,256,256, 16384,64,64,64,
                              65536,262144,1024,1024, 65536,262144,1024,1024,
                              32768,64,32768,64};
  {
    int acc = 0;
    for (int k = 0; k < 24; ++k){ ca.src[k] = d_in[2 + k]; ca.off[k] = acc; acc += wsz[k]; }
    ca.off[24] = acc;
  }
  int nblk = (SP_TOTAL + 255) / 256 + 1;
  setup_kernel<<<nblk, 256, 0, stream>>>(ca, Wbuf, BBF, Pb, WT, HX,
                                         d_in[0], ei, csr_row, csr_src);

  glayer_kernel<16><<<512, 256, 0, stream>>>(Pb, BBF + BOFF_G0, Wbuf,
                                             WOFF_G0AS, WOFF_G0AD, WOFF_G0B,
                                             csr_row, csr_src, PA);
  glayer_kernel<256><<<512, 256, 0, stream>>>(PA, BBF + BOFF_G1, Wbuf,
                                              WOFF_G1AS, WOFF_G1AD, WOFF_G1B,
                                              csr_row, csr_src, PB);
  glayer2_kernel<<<512, 256, 0, stream>>>(PB, BBF + BOFF_G2, Wbuf,
                                          csr_row, csr_src, XSEQ);

  mmx2_kernel<<<dim3(4, 16, 2), 256, 0, stream>>>(XSEQ, BBF + BOFF_WF, BBF + BOFF_WB,
                                                  XFp, XBp, 256, 1024, 64);

  lstm13_kernel<<<LSTM_GRID, 256, 0, stream>>>(XFp, XBp, WT,
                                               Wbuf + WOFF_BIHF, Wbuf + WOFF_BHHF,
                                               Wbuf + WOFF_BIHB, Wbuf + WOFF_BHHB,
                                               HX, HT);

  head2_kernel<<<1, 512, 0, stream>>>(HT, Wbuf + WOFF_MUW, Wbuf + WOFF_MUB,
                                      Wbuf + WOFF_LVW, Wbuf + WOFF_LVB, (float*)d_out);
}